// Round 4
// baseline (1453.442 us; speedup 1.0000x reference)
//
#include <hip/hip_runtime.h>
#include <math.h>

// Problem dims
#define B_   8
#define T_   64
#define N_   200
#define CIN_ 200
#define C_   128
#define L_   2
#define NC_  2
#define S_   100
#define BT_  512      // B*T
#define RB_  102400   // B*T*N

#define ACT_NONE 0
#define ACT_RELU 1
#define ACT_GELU 2

typedef __attribute__((ext_vector_type(8))) short short8v;
typedef __attribute__((ext_vector_type(4))) float f32x4v;

__device__ __forceinline__ unsigned short f2bf(float f) {
    unsigned u = __float_as_uint(f);
    unsigned r = (u + 0x7FFFu + ((u >> 16) & 1u)) >> 16;   // RNE
    return (unsigned short)r;
}
__device__ __forceinline__ float bf2f(unsigned short u) {
    return __uint_as_float(((unsigned)u) << 16);
}
__device__ __forceinline__ float bflo(unsigned u) { return __uint_as_float(u << 16); }
__device__ __forceinline__ float bfhi(unsigned u) { return __uint_as_float(u & 0xFFFF0000u); }
__device__ __forceinline__ unsigned packbf(float a, float b) {
    return (unsigned)f2bf(a) | ((unsigned)f2bf(b) << 16);
}

// ============================================================================
// thr_kernel: per-(b,t) 70th percentile (exact order stats s[27999], s[28000])
__device__ __forceinline__ void thr_process(float v, int lane, int& c_lo,
                                            int* s_cnt, float* cand, int* hist) {
    bool isc = false;
    if (v < 0.65f) {
        c_lo++;
    } else if (v < 0.75f) {
        isc = true;
        int bin = (int)((v - 0.65f) * 10240.0f);
        bin = bin < 0 ? 0 : (bin > 1023 ? 1023 : bin);
        atomicAdd(&hist[bin], 1);
    }
    unsigned long long mk = __ballot(isc);
    if (mk) {
        int ldr = __ffsll((unsigned long long)mk) - 1;
        int base = 0;
        if (lane == ldr) base = atomicAdd(s_cnt, __popcll(mk));
        base = __shfl(base, ldr);
        if (isc) {
            int p = base + __popcll(mk & ((1ull << lane) - 1ull));
            if (p < 6144) cand[p] = v;
        }
    }
}

__global__ __launch_bounds__(512) void thr_kernel(const float* __restrict__ a,
                                                  float* __restrict__ thr) {
    __shared__ int   hist[1024];
    __shared__ float cand[6144];
    __shared__ int   red[512];
    __shared__ int   part[256];
    __shared__ int   grp[32];
    __shared__ float cand2[256];
    __shared__ int   meta[8];
    int tid = threadIdx.x, lane = tid & 63;
    int bt = blockIdx.x;
    for (int i = tid; i < 1024; i += 512) hist[i] = 0;
    if (tid == 0) { meta[0] = 0; meta[1] = 0; }
    __syncthreads();

    const float4* x4 = (const float4*)(a + (long)bt * 40000);
    int c_lo = 0;
    for (int i4 = tid; i4 < 10000; i4 += 512) {
        float4 v = x4[i4];
        thr_process(v.x, lane, c_lo, &meta[0], cand, hist);
        thr_process(v.y, lane, c_lo, &meta[0], cand, hist);
        thr_process(v.z, lane, c_lo, &meta[0], cand, hist);
        thr_process(v.w, lane, c_lo, &meta[0], cand, hist);
    }
    red[tid] = c_lo;
    __syncthreads();
    for (int off = 256; off; off >>= 1) {
        if (tid < off) red[tid] += red[tid + off];
        __syncthreads();
    }
    int c_lo_tot = red[0];
    if (tid < 256) part[tid] = hist[4*tid] + hist[4*tid+1] + hist[4*tid+2] + hist[4*tid+3];
    __syncthreads();
    if (tid < 32) {
        int s = 0;
        for (int i = 0; i < 8; i++) s += part[8*tid + i];
        grp[tid] = s;
    }
    __syncthreads();
    if (tid == 0) {
        int r = 27999 - c_lo_tot;
        int cum = 0, g = 0;
        while (cum + grp[g] <= r) cum += grp[g++];
        int t = g * 8;
        while (cum + part[t] <= r) cum += part[t++];
        int b = t * 4;
        while (cum + hist[b] <= r) cum += hist[b++];
        meta[2] = b; meta[3] = cum;
        int r1 = r + 1;
        cum = 0; g = 0;
        while (cum + grp[g] <= r1) cum += grp[g++];
        t = g * 8;
        while (cum + part[t] <= r1) cum += part[t++];
        b = t * 4;
        while (cum + hist[b] <= r1) cum += hist[b++];
        meta[4] = b; meta[5] = r;
    }
    __syncthreads();
    int blo = meta[2], base = meta[3], bhi = meta[4], r = meta[5];
    int m = meta[0]; if (m > 6144) m = 6144;
    for (int i = tid; i < m; i += 512) {
        float v = cand[i];
        int bin = (int)((v - 0.65f) * 10240.0f);
        bin = bin < 0 ? 0 : (bin > 1023 ? 1023 : bin);
        if (bin >= blo && bin <= bhi) {
            int p = atomicAdd(&meta[1], 1);
            if (p < 256) cand2[p] = v;
        }
    }
    __syncthreads();
    if (tid == 0) {
        int m2 = meta[1]; if (m2 > 256) m2 = 256;
        for (int i = 1; i < m2; i++) {
            float key = cand2[i]; int j = i - 1;
            while (j >= 0 && cand2[j] > key) { cand2[j+1] = cand2[j]; j--; }
            cand2[j+1] = key;
        }
        float s1 = cand2[r - base], s2 = cand2[r + 1 - base];
        thr[bt] = s1 * 0.701171875f + s2 * 0.298828125f;
    }
}

// ============================================================================
// wtcvt: weight (K x 128) fp32 -> wt (128 x Kpad) bf16, k-contiguous, zero-padded
__global__ void wtcvt_kernel(const float* __restrict__ w, int K, int Kpad,
                             unsigned short* __restrict__ wt) {
    int c = blockIdx.x;                    // 128 blocks
    for (int k = threadIdx.x; k < Kpad; k += 64) {
        float v = (k < K) ? w[(long)k * 128 + c] : 0.f;
        wt[(long)c * Kpad + k] = f2bf(v);
    }
}

// ============================================================================
// mfma_mm: (102400 x K) @ wt(128 x Kpad bf16, k-contig) -> y (102400 x 128) bf16
// A input either fp32 (K arbitrary) or bf16 (K%32==0). Optional fused BN+ReLU
// on input (bf16 path). 128x128 tile, 4 waves x (32 rows x 128 cols), K chunk 32.
template<bool A_BF16, bool BN_IN, bool BIAS_OUT>
__global__ __launch_bounds__(256) void mfma_mm_kernel(
        const void* __restrict__ xv, int K, int Kstride,
        const unsigned short* __restrict__ wt, int Kpad,
        const float* __restrict__ bias, const float* __restrict__ stats,
        const float* __restrict__ bng, const float* __restrict__ bnb,
        unsigned short* __restrict__ y) {
    __shared__ unsigned short sA[128 * 40];   // rows x 32k (+8 pad)
    __shared__ unsigned short sB[128 * 40];   // cols x 32k (+8 pad)
    __shared__ float bnS[128], bnB[128];
    int tid = threadIdx.x;
    if (BN_IN) {
        if (tid < 128) {
            float mm = stats[tid] * (1.f / (float)RB_);
            float var = fmaxf(stats[128 + tid] * (1.f / (float)RB_) - mm * mm, 0.f);
            float sc = bng[tid] / sqrtf(var + 1e-5f);
            bnS[tid] = sc; bnB[tid] = bnb[tid] - mm * sc;
        }
        __syncthreads();
    }
    long rowBase = (long)blockIdx.x * 128;
    int wave = tid >> 6, lane = tid & 63;
    int quad = lane >> 4, m16 = lane & 15;

    f32x4v acc[2][8];
    #pragma unroll
    for (int i = 0; i < 2; i++)
        #pragma unroll
        for (int j = 0; j < 8; j++) acc[i][j] = (f32x4v){0.f, 0.f, 0.f, 0.f};

    int nChunks = (K + 31) >> 5;
    for (int kc = 0; kc < nChunks; kc++) {
        int k0 = kc << 5;
        if (A_BF16) {
            const unsigned short* xb = (const unsigned short*)xv;
            // 128 rows x 32 k bf16 = 512 uint4
            for (int idx = tid; idx < 512; idx += 256) {
                int r = idx >> 2, q = (idx & 3) << 3;
                uint4 u = *(const uint4*)&xb[(rowBase + r) * Kstride + k0 + q];
                if (BN_IN) {
                    int k = k0 + q;
                    float f0 = fmaxf(bflo(u.x) * bnS[k]   + bnB[k],   0.f);
                    float f1 = fmaxf(bfhi(u.x) * bnS[k+1] + bnB[k+1], 0.f);
                    float f2 = fmaxf(bflo(u.y) * bnS[k+2] + bnB[k+2], 0.f);
                    float f3 = fmaxf(bfhi(u.y) * bnS[k+3] + bnB[k+3], 0.f);
                    float f4 = fmaxf(bflo(u.z) * bnS[k+4] + bnB[k+4], 0.f);
                    float f5 = fmaxf(bfhi(u.z) * bnS[k+5] + bnB[k+5], 0.f);
                    float f6 = fmaxf(bflo(u.w) * bnS[k+6] + bnB[k+6], 0.f);
                    float f7 = fmaxf(bfhi(u.w) * bnS[k+7] + bnB[k+7], 0.f);
                    u.x = packbf(f0, f1); u.y = packbf(f2, f3);
                    u.z = packbf(f4, f5); u.w = packbf(f6, f7);
                }
                *(uint4*)&sA[r * 40 + q] = u;
            }
        } else {
            const float* x = (const float*)xv;
            for (int idx = tid; idx < 1024; idx += 256) {
                int r = idx >> 3, kq = (idx & 7) << 2;
                int kk = k0 + kq;
                float4 v = {0.f, 0.f, 0.f, 0.f};
                if (kk + 3 < K) {
                    v = *(const float4*)&x[(rowBase + r) * Kstride + kk];
                } else if (kk < K) {
                    float tmp[4] = {0.f, 0.f, 0.f, 0.f};
                    for (int j = 0; j < 4; j++)
                        if (kk + j < K) tmp[j] = x[(rowBase + r) * Kstride + kk + j];
                    v.x = tmp[0]; v.y = tmp[1]; v.z = tmp[2]; v.w = tmp[3];
                }
                ushort4 o = {f2bf(v.x), f2bf(v.y), f2bf(v.z), f2bf(v.w)};
                *(ushort4*)&sA[r * 40 + kq] = o;
            }
        }
        // ---- stage B (bf16, k-contiguous; Kpad multiple of 32)
        for (int idx = tid; idx < 512; idx += 256) {
            int c = idx >> 2, q = (idx & 3) << 3;
            *(uint4*)&sB[c * 40 + q] = *(const uint4*)&wt[(long)c * Kpad + k0 + q];
        }
        __syncthreads();
        // ---- MFMA
        int r0 = wave * 32;
        short8v afrag[2];
        #pragma unroll
        for (int rt = 0; rt < 2; rt++)
            afrag[rt] = *(const short8v*)&sA[(r0 + rt * 16 + m16) * 40 + quad * 8];
        #pragma unroll
        for (int ct = 0; ct < 8; ct++) {
            short8v bfrag = *(const short8v*)&sB[(ct * 16 + m16) * 40 + quad * 8];
            acc[0][ct] = __builtin_amdgcn_mfma_f32_16x16x32_bf16(afrag[0], bfrag, acc[0][ct], 0, 0, 0);
            acc[1][ct] = __builtin_amdgcn_mfma_f32_16x16x32_bf16(afrag[1], bfrag, acc[1][ct], 0, 0, 0);
        }
        __syncthreads();
    }
    // ---- epilogue (bf16 out)
    #pragma unroll
    for (int rt = 0; rt < 2; rt++) {
        #pragma unroll
        for (int ct = 0; ct < 8; ct++) {
            int col = ct * 16 + m16;
            float bv = BIAS_OUT ? bias[col] : 0.f;
            long row = rowBase + wave * 32 + rt * 16 + quad * 4;
            #pragma unroll
            for (int i = 0; i < 4; i++)
                y[(row + i) * 128 + col] = f2bf(acc[rt][ct][i] + bv);
        }
    }
}

// ============================================================================
// maskagg v3: y2 = mask @ zh + eps*zh + b1  (bf16 zh in, bf16 y2 out)
// XCD-swizzled so all 25 blocks of one bt land on one XCD (zh L2 locality).
// Mask layout [i][j+pad]: conflict-free writes, broadcast b128 reads.
__global__ __launch_bounds__(128) void maskagg_kernel(
        const float* __restrict__ a, const float* __restrict__ thr,
        const unsigned short* __restrict__ zh, const float* __restrict__ geps, int l,
        const float* __restrict__ b1, unsigned short* __restrict__ y) {
    __shared__ float smask[8 * 208];   // [i][j], stride 208
    int g = blockIdx.x;
    int xcd = g & 7, idx = g >> 3;            // 1600 per XCD
    int bt = xcd * 64 + idx / 25;
    int i0 = (idx % 25) * 8;
    float th = thr[bt];
    const float* arow = a + ((long)bt * N_ + i0) * N_;
    for (int t = threadIdx.x; t < 8 * N_; t += 128) {
        int i = t / N_, j = t - i * N_;
        smask[i * 208 + j] = (arow[i * N_ + j] > th) ? 1.f : 0.f;
    }
    __syncthreads();
    int c = threadIdx.x;
    const unsigned short* zbt = zh + (long)bt * N_ * C_;
    float acc[8] = {0.f,0.f,0.f,0.f,0.f,0.f,0.f,0.f};
    for (int j0 = 0; j0 < N_; j0 += 4) {
        float z0 = bf2f(zbt[(j0 + 0) * C_ + c]);
        float z1 = bf2f(zbt[(j0 + 1) * C_ + c]);
        float z2 = bf2f(zbt[(j0 + 2) * C_ + c]);
        float z3 = bf2f(zbt[(j0 + 3) * C_ + c]);
        #pragma unroll
        for (int i = 0; i < 8; i++) {
            float4 m4 = *(const float4*)&smask[i * 208 + j0];   // wave-broadcast
            acc[i] = fmaf(m4.x, z0, acc[i]);
            acc[i] = fmaf(m4.y, z1, acc[i]);
            acc[i] = fmaf(m4.z, z2, acc[i]);
            acc[i] = fmaf(m4.w, z3, acc[i]);
        }
    }
    float eps = geps[l];
    float bv = b1[c];
    #pragma unroll
    for (int i = 0; i < 8; i++) {
        float ev = bf2f(zbt[(i0 + i) * C_ + c]);
        y[((long)bt * N_ + i0 + i) * C_ + c] = f2bf(acc[i] + eps * ev + bv);
    }
}

// ---------------- column sums & sumsq over bf16 tensor; stats pre-zeroed
__global__ __launch_bounds__(256) void colstats_bf16_kernel(
        const unsigned short* __restrict__ y, int rows_per_block, int R,
        float* __restrict__ stats) {
    int p = threadIdx.x & 63, sub = threadIdx.x >> 6;   // col-pair, row-phase
    int r0 = blockIdx.x * rows_per_block;
    float s0 = 0.f, ss0 = 0.f, s1 = 0.f, ss1 = 0.f;
    int rend = r0 + rows_per_block; if (rend > R) rend = R;
    for (int r = r0 + sub; r < rend; r += 4) {
        unsigned u = *(const unsigned*)&y[(long)r * C_ + p * 2];
        float a = bflo(u), b = bfhi(u);
        s0 += a; ss0 += a * a; s1 += b; ss1 += b * b;
    }
    atomicAdd(&stats[2 * p], s0);
    atomicAdd(&stats[2 * p + 1], s1);
    atomicAdd(&stats[C_ + 2 * p], ss0);
    atomicAdd(&stats[C_ + 2 * p + 1], ss1);
}

// ---------------- column sums & sumsq fp32 (small tensors)
__global__ void colstats_kernel(const float* __restrict__ y, int rows_per_block, int R,
                                float* __restrict__ stats) {
    int col = threadIdx.x & 127, sub = threadIdx.x >> 7;
    int r0 = blockIdx.x * rows_per_block;
    float s = 0.f, ss = 0.f;
    for (int r = r0 + sub; r < r0 + rows_per_block && r < R; r += 2) {
        float v = y[(long)r * C_ + col];
        s += v; ss += v * v;
    }
    atomicAdd(&stats[col], s);
    atomicAdd(&stats[C_ + col], ss);
}

// ---------------- apply BN (batch stats) + activation, in place (small tensors)
__global__ void bnact_kernel(float* __restrict__ y, int R, const float* __restrict__ stats,
                             const float* __restrict__ g, const float* __restrict__ b, int act) {
    long idx = (long)blockIdx.x * blockDim.x + threadIdx.x;
    if (idx >= (long)R * C_) return;
    int col = idx & (C_ - 1);
    float m   = stats[col] / (float)R;
    float var = fmaxf(stats[C_ + col] / (float)R - m * m, 0.f);
    float inv = 1.f / sqrtf(var + 1e-5f);
    float v = (y[idx] - m) * inv * g[col] + b[col];
    if (act == ACT_RELU)      v = fmaxf(v, 0.f);
    else if (act == ACT_GELU) v = 0.5f * v * (1.f + erff(v * 0.70710678118654752f));
    y[idx] = v;
}

// ---------------- xr[tb][c] = mean_n relu(bn2(raw))   (bf16 raw, BN fused)
__global__ __launch_bounds__(128) void xr2_kernel(const unsigned short* __restrict__ raw,
                                                  const float* __restrict__ stats,
                                                  const float* __restrict__ g,
                                                  const float* __restrict__ b,
                                                  float* __restrict__ xr) {
    int t = blockIdx.x / B_, bb = blockIdx.x % B_;
    const unsigned short* base = raw + ((long)bb * T_ + t) * N_ * C_;
    int c = threadIdx.x;
    float m = stats[c] * (1.f / (float)RB_);
    float var = fmaxf(stats[128 + c] * (1.f / (float)RB_) - m * m, 0.f);
    float sc = g[c] / sqrtf(var + 1e-5f);
    float sh = b[c] - m * sc;
    float s = 0.f;
    for (int n = 0; n < N_; n++) s += fmaxf(fmaf(bf2f(base[n * C_ + c]), sc, sh), 0.f);
    xr[(long)blockIdx.x * C_ + c] = s * (1.f / 200.f);
}

// ---------------- hr[tb][c] = mean_n relu(bn2(raw)) * ga[tb][n]  (bf16 raw)
__global__ __launch_bounds__(128) void hr2_kernel(const unsigned short* __restrict__ raw,
                                                  const float* __restrict__ stats,
                                                  const float* __restrict__ g,
                                                  const float* __restrict__ b,
                                                  const float* __restrict__ ga,
                                                  float* __restrict__ hr) {
    __shared__ float sga[N_];
    int t = blockIdx.x / B_, bb = blockIdx.x % B_;
    const unsigned short* base = raw + ((long)bb * T_ + t) * N_ * C_;
    for (int i = threadIdx.x; i < N_; i += blockDim.x) sga[i] = ga[(long)blockIdx.x * N_ + i];
    __syncthreads();
    int c = threadIdx.x;
    float m = stats[c] * (1.f / (float)RB_);
    float var = fmaxf(stats[128 + c] * (1.f / (float)RB_) - m * m, 0.f);
    float sc = g[c] / sqrtf(var + 1e-5f);
    float sh = b[c] - m * sc;
    float s = 0.f;
    for (int n = 0; n < N_; n++)
        s = fmaf(fmaxf(fmaf(bf2f(base[n * C_ + c]), sc, sh), 0.f), sga[n], s);
    hr[(long)blockIdx.x * C_ + c] = s * (1.f / 200.f);
}

// ---------------- generic small (R x K) @ (K x Cout) + bias, blockDim == Cout
template<int K, int ROWS>
__global__ void mm_kernel(const float* __restrict__ x, const float* __restrict__ w,
                          const float* __restrict__ bias, float* __restrict__ y,
                          int Cout, int act) {
    __shared__ float sx[ROWS * K];
    long r0 = (long)blockIdx.x * ROWS;
    for (int idx = threadIdx.x; idx < ROWS * K; idx += blockDim.x)
        sx[idx] = x[r0 * K + idx];
    __syncthreads();
    int c = threadIdx.x;
    float acc[ROWS];
    #pragma unroll
    for (int i = 0; i < ROWS; i++) acc[i] = 0.f;
    for (int k = 0; k < K; k++) {
        float wv = w[k * Cout + c];
        #pragma unroll
        for (int i = 0; i < ROWS; i++) acc[i] = fmaf(sx[i * K + k], wv, acc[i]);
    }
    float bv = bias ? bias[c] : 0.f;
    for (int i = 0; i < ROWS; i++) {
        float vv = acc[i] + bv;
        if (act == ACT_RELU) vv = fmaxf(vv, 0.f);
        y[(r0 + i) * Cout + c] = vv;
    }
}

// ---------------- ga = sigmoid(e @ aw + ab), write ws (t,b,n) and node_attn (b,l,t,n)
__global__ void ga_kernel(const float* __restrict__ e, const float* __restrict__ aw,
                          const float* __restrict__ ab, float* __restrict__ ga,
                          float* __restrict__ node_out, int l) {
    __shared__ float sx[8 * C_];
    long r0 = (long)blockIdx.x * 8;
    for (int idx = threadIdx.x; idx < 8 * C_; idx += blockDim.x)
        sx[idx] = e[r0 * C_ + idx];
    __syncthreads();
    int c = threadIdx.x;
    if (c < N_) {
        float acc[8] = {0.f,0.f,0.f,0.f,0.f,0.f,0.f,0.f};
        for (int k = 0; k < C_; k++) {
            float wv = aw[k * N_ + c];
            #pragma unroll
            for (int i = 0; i < 8; i++) acc[i] = fmaf(sx[i * C_ + k], wv, acc[i]);
        }
        float bv = ab[c];
        for (int i = 0; i < 8; i++) {
            int tb = (int)r0 + i;
            int t = tb / B_, b = tb % B_;
            float v = 1.f / (1.f + expf(-(acc[i] + bv)));
            ga[(long)tb * N_ + c] = v;
            node_out[(((long)b * L_ + l) * T_ + t) * N_ + c] = v;
        }
    }
}

// ---------------- attention scores + softmax over s; write time_attn (b,l,t,s)
__global__ void attn_kernel(const float* __restrict__ qkv, float* __restrict__ time_out, int l) {
    __shared__ float q[C_];
    int b = blockIdx.x / T_, t = blockIdx.x % T_;
    int tid = threadIdx.x;  // 64 threads = 1 wave; tid = s
    for (int idx = tid; idx < C_; idx += 64) q[idx] = qkv[((long)t * B_ + b) * 384 + idx];
    __syncthreads();
    const float* krow = qkv + ((long)tid * B_ + b) * 384 + C_;
    float s = 0.f;
    for (int c = 0; c < C_; c++) s = fmaf(q[c], krow[c], s);
    s *= 0.08838834764831843f;
    float mx = s;
    #pragma unroll
    for (int off = 32; off; off >>= 1) mx = fmaxf(mx, __shfl_xor(mx, off));
    float e = expf(s - mx), sum = e;
    #pragma unroll
    for (int off = 32; off; off >>= 1) sum += __shfl_xor(sum, off);
    time_out[(((long)b * L_ + l) * T_ + t) * T_ + tid] = e / sum;
}

// ---------------- attv[tb][c] = sum_s A[b][t][s] * v[s][b][c]
__global__ void attv_kernel(const float* __restrict__ A, const float* __restrict__ qkv,
                            float* __restrict__ attv, int l) {
    __shared__ float sa[T_];
    int t = blockIdx.x / B_, b = blockIdx.x % B_;
    for (int i = threadIdx.x; i < T_; i += blockDim.x)
        sa[i] = A[(((long)b * L_ + l) * T_ + t) * T_ + i];
    __syncthreads();
    int c = threadIdx.x;
    float s = 0.f;
    for (int sp = 0; sp < T_; sp++) s = fmaf(sa[sp], qkv[((long)sp * B_ + b) * 384 + 256 + c], s);
    attv[(long)blockIdx.x * C_ + c] = s;
}

// ---------------- LayerNorm over last dim (C_), optional residual add
__global__ void ln_kernel(const float* __restrict__ x, const float* __restrict__ x2,
                          const float* __restrict__ g, const float* __restrict__ b,
                          float* __restrict__ out) {
    __shared__ float red[C_];
    int r = blockIdx.x, c = threadIdx.x;
    float v = x[(long)r * C_ + c];
    if (x2) v += x2[(long)r * C_ + c];
    red[c] = v; __syncthreads();
    for (int off = 64; off; off >>= 1) { if (c < off) red[c] += red[c + off]; __syncthreads(); }
    float m = red[0] * (1.f / C_); __syncthreads();
    float d = v - m;
    red[c] = d * d; __syncthreads();
    for (int off = 64; off; off >>= 1) { if (c < off) red[c] += red[c + off]; __syncthreads(); }
    float var = red[0] * (1.f / C_);
    out[(long)r * C_ + c] = d * (1.f / sqrtf(var + 1e-5f)) * g[c] + b[c];
}

// ---------------- lat[b][c] = sum_t x2[tb][c]
__global__ void latsum_kernel(const float* __restrict__ x2, float* __restrict__ lat) {
    int b = blockIdx.x, c = threadIdx.x;
    float s = 0.f;
    for (int t = 0; t < T_; t++) s += x2[((long)t * B_ + b) * C_ + c];
    lat[(long)b * C_ + c] = s;
}

// ---------------- logit + feat_fMRI
__global__ void final_kernel(const float* __restrict__ lat, const float* __restrict__ cls_w,
                             const float* __restrict__ cls_b, float* __restrict__ out) {
    int idx = blockIdx.x * blockDim.x + threadIdx.x;
    if (idx < B_ * NC_) {
        int b = idx / NC_, nc = idx % NC_;
        float s = 0.f;
        for (int l = 0; l < L_; l++) {
            float acc = 0.f;
            for (int c = 0; c < C_; c++)
                acc = fmaf(lat[l * B_ * C_ + b * C_ + c], cls_w[l * C_ * NC_ + c * NC_ + nc], acc);
            s += acc + cls_b[l * NC_ + nc];
        }
        out[idx] = s;
    } else if (idx < B_ * NC_ + B_ * C_) {
        int j = idx - B_ * NC_;
        out[idx] = 0.5f * (lat[j] + lat[B_ * C_ + j]);
    }
}

// ---------------- feat_sMRI = bn(trad @ smri_w + smri_b) over batch of 8
__global__ void smri_kernel(const float* __restrict__ trad, const float* __restrict__ w,
                            const float* __restrict__ bias, const float* __restrict__ g,
                            const float* __restrict__ bb, float* __restrict__ out) {
    int c = threadIdx.x;
    float y[B_];
    for (int b = 0; b < B_; b++) {
        float s = bias[c];
        for (int k = 0; k < S_; k++) s = fmaf(trad[b * S_ + k], w[k * C_ + c], s);
        y[b] = s;
    }
    float m = 0.f;
    for (int b = 0; b < B_; b++) m += y[b];
    m *= (1.f / B_);
    float var = 0.f;
    for (int b = 0; b < B_; b++) { float d = y[b] - m; var += d * d; }
    var *= (1.f / B_);
    float inv = 1.f / sqrtf(var + 1e-5f);
    for (int b = 0; b < B_; b++) out[b * C_ + c] = (y[b] - m) * inv * g[c] + bb[c];
}

// ============================================================================
extern "C" void kernel_launch(void* const* d_in, const int* in_sizes, int n_in,
                              void* d_out, int out_size, void* d_ws, size_t ws_size,
                              hipStream_t stream) {
    const float* fv       = (const float*)d_in[0];
    const float* fa       = (const float*)d_in[1];
    const float* trad     = (const float*)d_in[2];
    const float* w_init   = (const float*)d_in[6];
    const float* b_init   = (const float*)d_in[7];
    const float* gin_eps  = (const float*)d_in[8];
    const float* gin_w1   = (const float*)d_in[9];
    const float* gin_b1   = (const float*)d_in[10];
    const float* gbn1g    = (const float*)d_in[11];
    const float* gbn1b    = (const float*)d_in[12];
    const float* gin_w2   = (const float*)d_in[13];
    const float* gin_b2   = (const float*)d_in[14];
    const float* gbn2g    = (const float*)d_in[15];
    const float* gbn2b    = (const float*)d_in[16];
    const float* sero_w   = (const float*)d_in[17];
    const float* sero_b   = (const float*)d_in[18];
    const float* sbng     = (const float*)d_in[19];
    const float* sbnb     = (const float*)d_in[20];
    const float* sero_aw  = (const float*)d_in[21];
    const float* sero_ab  = (const float*)d_in[22];
    const float* wqkv     = (const float*)d_in[23];
    const float* bqkv     = (const float*)d_in[24];
    const float* wo       = (const float*)d_in[25];
    const float* bo       = (const float*)d_in[26];
    const float* ln1g     = (const float*)d_in[27];
    const float* ln1b     = (const float*)d_in[28];
    const float* ln2g     = (const float*)d_in[29];
    const float* ln2b     = (const float*)d_in[30];
    const float* tw1      = (const float*)d_in[31];
    const float* tb1      = (const float*)d_in[32];
    const float* tw2      = (const float*)d_in[33];
    const float* tb2      = (const float*)d_in[34];
    const float* cls_w    = (const float*)d_in[35];
    const float* cls_b    = (const float*)d_in[36];
    const float* smri_w   = (const float*)d_in[37];
    const float* smri_b   = (const float*)d_in[38];
    const float* smri_g   = (const float*)d_in[39];
    const float* smri_bb  = (const float*)d_in[40];

    float* out = (float*)d_out;

    // workspace layout
    const long SZ_BIG = (long)RB_ * C_;            // 13,107,200 elements
    unsigned short* H3b = (unsigned short*)d_ws;   // bf16 big buffers
    unsigned short* Y1b = H3b + SZ_BIG;
    unsigned short* Y2b = Y1b + SZ_BIG;
    float* fbase = (float*)(Y2b + SZ_BIG);
    float* THR  = fbase;                  // 512
    float* STAT = THR + 512;              // 256
    float* XR   = STAT + 256;             // 512*128
    float* E    = XR  + BT_ * C_;
    float* GA   = E   + BT_ * C_;         // 512*200
    float* HR   = GA  + BT_ * N_;
    float* QKV  = HR  + BT_ * C_;         // 512*384
    float* ATTV = QKV + BT_ * 3 * C_;
    float* ATT  = ATTV + BT_ * C_;
    float* X1   = ATT + BT_ * C_;
    float* MMB  = X1  + BT_ * C_;         // 512*256 (FFN scratch)
    float* X2   = MMB + BT_ * 2 * C_;
    float* LAT  = X2  + BT_ * C_;         // 2*8*128
    float* STATB = MMB;   // overlay: BN2 stats; lifetime disjoint from FFN scratch
    unsigned short* WT0 = (unsigned short*)(LAT + L_ * B_ * C_);  // w_init^T: 128 x 224
    unsigned short* WT1 = WT0 + 128 * 224;                        // gin_w1^T: 2 x (128x128)
    unsigned short* WT2 = WT1 + 2 * 128 * 128;                    // gin_w2^T: 2 x (128x128)

    // output layout (floats)
    float* OUT_LOGIT = out;            // 16 logit + 1024 feat_fMRI
    float* OUT_FEATS = out + 1040;     // 1024 (feat_sMRI)
    float* OUT_NODE  = out + 2064;     // 204800
    float* OUT_TIME  = out + 206864;   // 65536

    // ---- one-shot weight transpose+cvt (tiny)
    wtcvt_kernel<<<128, 64, 0, stream>>>(w_init, 200, 224, WT0);
    wtcvt_kernel<<<128, 64, 0, stream>>>(gin_w1,           128, 128, WT1);
    wtcvt_kernel<<<128, 64, 0, stream>>>(gin_w1 + C_ * C_, 128, 128, WT1 + 128 * 128);
    wtcvt_kernel<<<128, 64, 0, stream>>>(gin_w2,           128, 128, WT2);
    wtcvt_kernel<<<128, 64, 0, stream>>>(gin_w2 + C_ * C_, 128, 128, WT2 + 128 * 128);

    // h3 = fv @ w_init + b_init   (fp32 in, bf16 out)
    mfma_mm_kernel<false, false, true><<<RB_ / 128, 256, 0, stream>>>(
        fv, 200, 200, WT0, 224, b_init, nullptr, nullptr, nullptr, H3b);
    thr_kernel<<<BT_, 512, 0, stream>>>(fa, THR);

    for (int l = 0; l < L_; l++) {
        // zh = h3 @ w1 (bf16 in/out); y2 = mask@zh + eps*zh + b1 (bf16)
        mfma_mm_kernel<true, false, false><<<RB_ / 128, 256, 0, stream>>>(
            H3b, 128, 128, WT1 + l * 128 * 128, 128, nullptr, nullptr, nullptr, nullptr, Y1b);
        maskagg_kernel<<<BT_ * 25, 128, 0, stream>>>(fa, THR, Y1b, gin_eps, l, gin_b1 + l * C_, Y2b);
        hipMemsetAsync(STAT, 0, 256 * sizeof(float), stream);
        colstats_bf16_kernel<<<RB_ / 256, 256, 0, stream>>>(Y2b, 256, RB_, STAT);
        // Y1raw = relu(bn1(Y2)) @ w2 + b2   (BN+relu fused into staging)
        mfma_mm_kernel<true, true, true><<<RB_ / 128, 256, 0, stream>>>(
            Y2b, 128, 128, WT2 + l * 128 * 128, 128, gin_b2 + l * C_, STAT,
            gbn1g + l * C_, gbn1b + l * C_, Y1b);
        hipMemsetAsync(STATB, 0, 256 * sizeof(float), stream);
        colstats_bf16_kernel<<<RB_ / 256, 256, 0, stream>>>(Y1b, 256, RB_, STATB);
        // hb = relu(bn2(Y1raw)) applied on-the-fly in xr2/hr2
        xr2_kernel<<<BT_, 128, 0, stream>>>(Y1b, STATB, gbn2g + l * C_, gbn2b + l * C_, XR);

        mm_kernel<128, 8><<<BT_ / 8, 128, 0, stream>>>(XR, sero_w + l * C_ * C_, sero_b + l * C_, E, C_, ACT_NONE);
        hipMemsetAsync(STAT, 0, 256 * sizeof(float), stream);
        colstats_kernel<<<2, 256, 0, stream>>>(E, 256, BT_, STAT);
        bnact_kernel<<<(BT_ * C_) / 256, 256, 0, stream>>>(E, BT_, STAT, sbng + l * C_, sbnb + l * C_, ACT_GELU);

        ga_kernel<<<BT_ / 8, 256, 0, stream>>>(E, sero_aw + l * C_ * N_, sero_ab + l * N_, GA, OUT_NODE, l);
        hr2_kernel<<<BT_, 128, 0, stream>>>(Y1b, STATB, gbn2g + l * C_, gbn2b + l * C_, GA, HR);

        mm_kernel<128, 8><<<BT_ / 8, 384, 0, stream>>>(HR, wqkv + l * C_ * 3 * C_, bqkv + l * 3 * C_, QKV, 3 * C_, ACT_NONE);
        attn_kernel<<<B_ * T_, 64, 0, stream>>>(QKV, OUT_TIME, l);
        attv_kernel<<<BT_, 128, 0, stream>>>(OUT_TIME, QKV, ATTV, l);
        mm_kernel<128, 8><<<BT_ / 8, 128, 0, stream>>>(ATTV, wo + l * C_ * C_, bo + l * C_, ATT, C_, ACT_NONE);
        ln_kernel<<<BT_, 128, 0, stream>>>(ATT, nullptr, ln1g + l * C_, ln1b + l * C_, X1);
        mm_kernel<128, 8><<<BT_ / 8, 256, 0, stream>>>(X1, tw1 + l * C_ * 2 * C_, tb1 + l * 2 * C_, MMB, 2 * C_, ACT_RELU);
        mm_kernel<256, 8><<<BT_ / 8, 128, 0, stream>>>(MMB, tw2 + l * 2 * C_ * C_, tb2 + l * C_, ATTV, C_, ACT_NONE);
        ln_kernel<<<BT_, 128, 0, stream>>>(X1, ATTV, ln2g + l * C_, ln2b + l * C_, X2);
        latsum_kernel<<<B_, 128, 0, stream>>>(X2, LAT + l * B_ * C_);
    }

    final_kernel<<<5, 256, 0, stream>>>(LAT, cls_w, cls_b, OUT_LOGIT);
    smri_kernel<<<1, 128, 0, stream>>>(trad, smri_w, smri_b, smri_g, smri_bb, OUT_FEATS);
}

// Round 5
// 1419.117 us; speedup vs baseline: 1.0242x; 1.0242x over previous
//
#include <hip/hip_runtime.h>
#include <math.h>

// Problem dims
#define B_   8
#define T_   64
#define N_   200
#define CIN_ 200
#define C_   128
#define L_   2
#define NC_  2
#define S_   100
#define BT_  512      // B*T
#define RB_  102400   // B*T*N

#define ACT_NONE 0
#define ACT_RELU 1
#define ACT_GELU 2

typedef __attribute__((ext_vector_type(8))) short short8v;
typedef __attribute__((ext_vector_type(4))) float f32x4v;

__device__ __forceinline__ unsigned short f2bf(float f) {
    unsigned u = __float_as_uint(f);
    unsigned r = (u + 0x7FFFu + ((u >> 16) & 1u)) >> 16;   // RNE
    return (unsigned short)r;
}
__device__ __forceinline__ float bf2f(unsigned short u) {
    return __uint_as_float(((unsigned)u) << 16);
}
__device__ __forceinline__ float bflo(unsigned u) { return __uint_as_float(u << 16); }
__device__ __forceinline__ float bfhi(unsigned u) { return __uint_as_float(u & 0xFFFF0000u); }
__device__ __forceinline__ unsigned packbf(float a, float b) {
    return (unsigned)f2bf(a) | ((unsigned)f2bf(b) << 16);
}

// ============================================================================
// thr_kernel: per-(b,t) 70th percentile (exact order stats s[27999], s[28000])
__device__ __forceinline__ void thr_process(float v, int lane, int& c_lo,
                                            int* s_cnt, float* cand, int* hist) {
    bool isc = false;
    if (v < 0.65f) {
        c_lo++;
    } else if (v < 0.75f) {
        isc = true;
        int bin = (int)((v - 0.65f) * 10240.0f);
        bin = bin < 0 ? 0 : (bin > 1023 ? 1023 : bin);
        atomicAdd(&hist[bin], 1);
    }
    unsigned long long mk = __ballot(isc);
    if (mk) {
        int ldr = __ffsll((unsigned long long)mk) - 1;
        int base = 0;
        if (lane == ldr) base = atomicAdd(s_cnt, __popcll(mk));
        base = __shfl(base, ldr);
        if (isc) {
            int p = base + __popcll(mk & ((1ull << lane) - 1ull));
            if (p < 6144) cand[p] = v;
        }
    }
}

__global__ __launch_bounds__(512) void thr_kernel(const float* __restrict__ a,
                                                  float* __restrict__ thr) {
    __shared__ int   hist[1024];
    __shared__ float cand[6144];
    __shared__ int   red[512];
    __shared__ int   part[256];
    __shared__ int   grp[32];
    __shared__ float cand2[256];
    __shared__ int   meta[8];
    int tid = threadIdx.x, lane = tid & 63;
    int bt = blockIdx.x;
    for (int i = tid; i < 1024; i += 512) hist[i] = 0;
    if (tid == 0) { meta[0] = 0; meta[1] = 0; }
    __syncthreads();

    const float4* x4 = (const float4*)(a + (long)bt * 40000);
    int c_lo = 0;
    for (int i4 = tid; i4 < 10000; i4 += 512) {
        float4 v = x4[i4];
        thr_process(v.x, lane, c_lo, &meta[0], cand, hist);
        thr_process(v.y, lane, c_lo, &meta[0], cand, hist);
        thr_process(v.z, lane, c_lo, &meta[0], cand, hist);
        thr_process(v.w, lane, c_lo, &meta[0], cand, hist);
    }
    red[tid] = c_lo;
    __syncthreads();
    for (int off = 256; off; off >>= 1) {
        if (tid < off) red[tid] += red[tid + off];
        __syncthreads();
    }
    int c_lo_tot = red[0];
    if (tid < 256) part[tid] = hist[4*tid] + hist[4*tid+1] + hist[4*tid+2] + hist[4*tid+3];
    __syncthreads();
    if (tid < 32) {
        int s = 0;
        for (int i = 0; i < 8; i++) s += part[8*tid + i];
        grp[tid] = s;
    }
    __syncthreads();
    if (tid == 0) {
        int r = 27999 - c_lo_tot;
        int cum = 0, g = 0;
        while (cum + grp[g] <= r) cum += grp[g++];
        int t = g * 8;
        while (cum + part[t] <= r) cum += part[t++];
        int b = t * 4;
        while (cum + hist[b] <= r) cum += hist[b++];
        meta[2] = b; meta[3] = cum;
        int r1 = r + 1;
        cum = 0; g = 0;
        while (cum + grp[g] <= r1) cum += grp[g++];
        t = g * 8;
        while (cum + part[t] <= r1) cum += part[t++];
        b = t * 4;
        while (cum + hist[b] <= r1) cum += hist[b++];
        meta[4] = b; meta[5] = r;
    }
    __syncthreads();
    int blo = meta[2], base = meta[3], bhi = meta[4], r = meta[5];
    int m = meta[0]; if (m > 6144) m = 6144;
    for (int i = tid; i < m; i += 512) {
        float v = cand[i];
        int bin = (int)((v - 0.65f) * 10240.0f);
        bin = bin < 0 ? 0 : (bin > 1023 ? 1023 : bin);
        if (bin >= blo && bin <= bhi) {
            int p = atomicAdd(&meta[1], 1);
            if (p < 256) cand2[p] = v;
        }
    }
    __syncthreads();
    if (tid == 0) {
        int m2 = meta[1]; if (m2 > 256) m2 = 256;
        for (int i = 1; i < m2; i++) {
            float key = cand2[i]; int j = i - 1;
            while (j >= 0 && cand2[j] > key) { cand2[j+1] = cand2[j]; j--; }
            cand2[j+1] = key;
        }
        float s1 = cand2[r - base], s2 = cand2[r + 1 - base];
        thr[bt] = s1 * 0.701171875f + s2 * 0.298828125f;
    }
}

// ============================================================================
// wtcvt: weight (K x 128) fp32 -> wt (128 x Kpad) bf16, k-contiguous, zero-padded
__global__ void wtcvt_kernel(const float* __restrict__ w, int K, int Kpad,
                             unsigned short* __restrict__ wt) {
    int c = blockIdx.x;                    // 128 blocks
    for (int k = threadIdx.x; k < Kpad; k += 64) {
        float v = (k < K) ? w[(long)k * 128 + c] : 0.f;
        wt[(long)c * Kpad + k] = f2bf(v);
    }
}

// ============================================================================
// mfma_mm: (102400 x K) @ wt(128 x Kpad bf16, k-contig) -> y (102400 x 128) bf16
template<bool A_BF16, bool BN_IN, bool BIAS_OUT>
__global__ __launch_bounds__(256) void mfma_mm_kernel(
        const void* __restrict__ xv, int K, int Kstride,
        const unsigned short* __restrict__ wt, int Kpad,
        const float* __restrict__ bias, const float* __restrict__ stats,
        const float* __restrict__ bng, const float* __restrict__ bnb,
        unsigned short* __restrict__ y) {
    __shared__ unsigned short sA[128 * 40];   // rows x 32k (+8 pad)
    __shared__ unsigned short sB[128 * 40];   // cols x 32k (+8 pad)
    __shared__ float bnS[128], bnB[128];
    int tid = threadIdx.x;
    if (BN_IN) {
        if (tid < 128) {
            float mm = stats[tid] * (1.f / (float)RB_);
            float var = fmaxf(stats[128 + tid] * (1.f / (float)RB_) - mm * mm, 0.f);
            float sc = bng[tid] / sqrtf(var + 1e-5f);
            bnS[tid] = sc; bnB[tid] = bnb[tid] - mm * sc;
        }
        __syncthreads();
    }
    long rowBase = (long)blockIdx.x * 128;
    int wave = tid >> 6, lane = tid & 63;
    int quad = lane >> 4, m16 = lane & 15;

    f32x4v acc[2][8];
    #pragma unroll
    for (int i = 0; i < 2; i++)
        #pragma unroll
        for (int j = 0; j < 8; j++) acc[i][j] = (f32x4v){0.f, 0.f, 0.f, 0.f};

    int nChunks = (K + 31) >> 5;
    for (int kc = 0; kc < nChunks; kc++) {
        int k0 = kc << 5;
        if (A_BF16) {
            const unsigned short* xb = (const unsigned short*)xv;
            for (int idx = tid; idx < 512; idx += 256) {
                int r = idx >> 2, q = (idx & 3) << 3;
                uint4 u = *(const uint4*)&xb[(rowBase + r) * Kstride + k0 + q];
                if (BN_IN) {
                    int k = k0 + q;
                    float f0 = fmaxf(bflo(u.x) * bnS[k]   + bnB[k],   0.f);
                    float f1 = fmaxf(bfhi(u.x) * bnS[k+1] + bnB[k+1], 0.f);
                    float f2 = fmaxf(bflo(u.y) * bnS[k+2] + bnB[k+2], 0.f);
                    float f3 = fmaxf(bfhi(u.y) * bnS[k+3] + bnB[k+3], 0.f);
                    float f4 = fmaxf(bflo(u.z) * bnS[k+4] + bnB[k+4], 0.f);
                    float f5 = fmaxf(bfhi(u.z) * bnS[k+5] + bnB[k+5], 0.f);
                    float f6 = fmaxf(bflo(u.w) * bnS[k+6] + bnB[k+6], 0.f);
                    float f7 = fmaxf(bfhi(u.w) * bnS[k+7] + bnB[k+7], 0.f);
                    u.x = packbf(f0, f1); u.y = packbf(f2, f3);
                    u.z = packbf(f4, f5); u.w = packbf(f6, f7);
                }
                *(uint4*)&sA[r * 40 + q] = u;
            }
        } else {
            const float* x = (const float*)xv;
            for (int idx = tid; idx < 1024; idx += 256) {
                int r = idx >> 3, kq = (idx & 7) << 2;
                int kk = k0 + kq;
                float4 v = {0.f, 0.f, 0.f, 0.f};
                if (kk + 3 < K) {
                    v = *(const float4*)&x[(rowBase + r) * Kstride + kk];
                } else if (kk < K) {
                    float tmp[4] = {0.f, 0.f, 0.f, 0.f};
                    for (int j = 0; j < 4; j++)
                        if (kk + j < K) tmp[j] = x[(rowBase + r) * Kstride + kk + j];
                    v.x = tmp[0]; v.y = tmp[1]; v.z = tmp[2]; v.w = tmp[3];
                }
                ushort4 o = {f2bf(v.x), f2bf(v.y), f2bf(v.z), f2bf(v.w)};
                *(ushort4*)&sA[r * 40 + kq] = o;
            }
        }
        for (int idx = tid; idx < 512; idx += 256) {
            int c = idx >> 2, q = (idx & 3) << 3;
            *(uint4*)&sB[c * 40 + q] = *(const uint4*)&wt[(long)c * Kpad + k0 + q];
        }
        __syncthreads();
        int r0 = wave * 32;
        short8v afrag[2];
        #pragma unroll
        for (int rt = 0; rt < 2; rt++)
            afrag[rt] = *(const short8v*)&sA[(r0 + rt * 16 + m16) * 40 + quad * 8];
        #pragma unroll
        for (int ct = 0; ct < 8; ct++) {
            short8v bfrag = *(const short8v*)&sB[(ct * 16 + m16) * 40 + quad * 8];
            acc[0][ct] = __builtin_amdgcn_mfma_f32_16x16x32_bf16(afrag[0], bfrag, acc[0][ct], 0, 0, 0);
            acc[1][ct] = __builtin_amdgcn_mfma_f32_16x16x32_bf16(afrag[1], bfrag, acc[1][ct], 0, 0, 0);
        }
        __syncthreads();
    }
    #pragma unroll
    for (int rt = 0; rt < 2; rt++) {
        #pragma unroll
        for (int ct = 0; ct < 8; ct++) {
            int col = ct * 16 + m16;
            float bv = BIAS_OUT ? bias[col] : 0.f;
            long row = rowBase + wave * 32 + rt * 16 + quad * 4;
            #pragma unroll
            for (int i = 0; i < 4; i++)
                y[(row + i) * 128 + col] = f2bf(acc[rt][ct][i] + bv);
        }
    }
}

// ============================================================================
// maskagg v4 (MFMA): y2[bt] = (mask + eps*I) @ zh[bt] + b1,  bf16 in/out.
// One block per bt. M pad 256 (4 waves x 64 rows), K pad 224 (7 x 32), N=128.
// sA: bf16 mask chunk [256 rows][32k +8 pad]; sB: zh^T chunk [128 ch][32k +8 pad]
// built by in-LDS transpose. fa is L3-resident after thr_kernel.
__global__ __launch_bounds__(256) void maskagg_mfma_kernel(
        const float* __restrict__ a, const float* __restrict__ thr,
        const unsigned short* __restrict__ zh, const float* __restrict__ geps, int l,
        const float* __restrict__ b1, unsigned short* __restrict__ y) {
    __shared__ unsigned short sA[256 * 40];
    __shared__ unsigned short sB[128 * 40];
    int tid = threadIdx.x;
    int bt = blockIdx.x;
    float th = thr[bt];
    float eps = geps[l];
    const float* arow = a + (long)bt * N_ * N_;
    const unsigned short* zbt = zh + (long)bt * N_ * C_;
    int wave = tid >> 6, lane = tid & 63, quad = lane >> 4, m16 = lane & 15;

    f32x4v acc[4][8];
    #pragma unroll
    for (int i = 0; i < 4; i++)
        #pragma unroll
        for (int j = 0; j < 8; j++) acc[i][j] = (f32x4v){0.f, 0.f, 0.f, 0.f};

    int rr = tid >> 3, qq = (tid & 7) << 2;   // mask staging: 8 threads/row
    #pragma unroll 1
    for (int kc = 0; kc < 7; kc++) {
        int k0 = kc << 5;
        // ---- stage mask bf16 (+eps on diagonal)
        int k = k0 + qq;
        #pragma unroll
        for (int rb = 0; rb < 256; rb += 32) {
            int r = rb + rr;
            float4 v = {0.f, 0.f, 0.f, 0.f};
            if (r < N_ && k < N_)          // k%4==0 and 200%4==0 -> k+3<200 too
                v = *(const float4*)&arow[r * N_ + k];
            float m0 = (v.x > th ? 1.f : 0.f) + (r == k     ? eps : 0.f);
            float m1 = (v.y > th ? 1.f : 0.f) + (r == k + 1 ? eps : 0.f);
            float m2 = (v.z > th ? 1.f : 0.f) + (r == k + 2 ? eps : 0.f);
            float m3 = (v.w > th ? 1.f : 0.f) + (r == k + 3 ? eps : 0.f);
            ushort4 o = {f2bf(m0), f2bf(m1), f2bf(m2), f2bf(m3)};
            *(ushort4*)&sA[r * 40 + qq] = o;
        }
        // ---- stage zh^T (in-LDS transpose)
        #pragma unroll
        for (int pass = 0; pass < 2; pass++) {
            int idx = tid + pass * 256;
            int kk = idx & 31, c8 = (idx >> 5) << 3;
            int gk = k0 + kk;
            uint4 u = {0u, 0u, 0u, 0u};
            if (gk < N_) u = *(const uint4*)&zbt[gk * C_ + c8];
            sB[(c8 + 0) * 40 + kk] = (unsigned short)(u.x & 0xFFFFu);
            sB[(c8 + 1) * 40 + kk] = (unsigned short)(u.x >> 16);
            sB[(c8 + 2) * 40 + kk] = (unsigned short)(u.y & 0xFFFFu);
            sB[(c8 + 3) * 40 + kk] = (unsigned short)(u.y >> 16);
            sB[(c8 + 4) * 40 + kk] = (unsigned short)(u.z & 0xFFFFu);
            sB[(c8 + 5) * 40 + kk] = (unsigned short)(u.z >> 16);
            sB[(c8 + 6) * 40 + kk] = (unsigned short)(u.w & 0xFFFFu);
            sB[(c8 + 7) * 40 + kk] = (unsigned short)(u.w >> 16);
        }
        __syncthreads();
        // ---- MFMA: wave w covers rows w*64..w*64+63
        int rbase = wave * 64;
        short8v af[4];
        #pragma unroll
        for (int mt = 0; mt < 4; mt++)
            af[mt] = *(const short8v*)&sA[(rbase + mt * 16 + m16) * 40 + quad * 8];
        #pragma unroll
        for (int nt = 0; nt < 8; nt++) {
            short8v bf = *(const short8v*)&sB[(nt * 16 + m16) * 40 + quad * 8];
            #pragma unroll
            for (int mt = 0; mt < 4; mt++)
                acc[mt][nt] = __builtin_amdgcn_mfma_f32_16x16x32_bf16(af[mt], bf, acc[mt][nt], 0, 0, 0);
        }
        __syncthreads();
    }
    // ---- epilogue: + b1, bf16 store (rows < 200 only)
    #pragma unroll
    for (int nt = 0; nt < 8; nt++) {
        int col = nt * 16 + m16;
        float bv = b1[col];
        #pragma unroll
        for (int mt = 0; mt < 4; mt++) {
            int row = wave * 64 + mt * 16 + quad * 4;
            #pragma unroll
            for (int i = 0; i < 4; i++) {
                int rg = row + i;
                if (rg < N_)
                    y[((long)bt * N_ + rg) * C_ + col] = f2bf(acc[mt][nt][i] + bv);
            }
        }
    }
}

// ---------------- column sums & sumsq over bf16 tensor; stats pre-zeroed
__global__ __launch_bounds__(256) void colstats_bf16_kernel(
        const unsigned short* __restrict__ y, int rows_per_block, int R,
        float* __restrict__ stats) {
    int p = threadIdx.x & 63, sub = threadIdx.x >> 6;
    int r0 = blockIdx.x * rows_per_block;
    float s0 = 0.f, ss0 = 0.f, s1 = 0.f, ss1 = 0.f;
    int rend = r0 + rows_per_block; if (rend > R) rend = R;
    for (int r = r0 + sub; r < rend; r += 4) {
        unsigned u = *(const unsigned*)&y[(long)r * C_ + p * 2];
        float a = bflo(u), b = bfhi(u);
        s0 += a; ss0 += a * a; s1 += b; ss1 += b * b;
    }
    atomicAdd(&stats[2 * p], s0);
    atomicAdd(&stats[2 * p + 1], s1);
    atomicAdd(&stats[C_ + 2 * p], ss0);
    atomicAdd(&stats[C_ + 2 * p + 1], ss1);
}

// ---------------- column sums & sumsq fp32 (small tensors)
__global__ void colstats_kernel(const float* __restrict__ y, int rows_per_block, int R,
                                float* __restrict__ stats) {
    int col = threadIdx.x & 127, sub = threadIdx.x >> 7;
    int r0 = blockIdx.x * rows_per_block;
    float s = 0.f, ss = 0.f;
    for (int r = r0 + sub; r < r0 + rows_per_block && r < R; r += 2) {
        float v = y[(long)r * C_ + col];
        s += v; ss += v * v;
    }
    atomicAdd(&stats[col], s);
    atomicAdd(&stats[C_ + col], ss);
}

// ---------------- apply BN (batch stats) + activation, in place (small tensors)
__global__ void bnact_kernel(float* __restrict__ y, int R, const float* __restrict__ stats,
                             const float* __restrict__ g, const float* __restrict__ b, int act) {
    long idx = (long)blockIdx.x * blockDim.x + threadIdx.x;
    if (idx >= (long)R * C_) return;
    int col = idx & (C_ - 1);
    float m   = stats[col] / (float)R;
    float var = fmaxf(stats[C_ + col] / (float)R - m * m, 0.f);
    float inv = 1.f / sqrtf(var + 1e-5f);
    float v = (y[idx] - m) * inv * g[col] + b[col];
    if (act == ACT_RELU)      v = fmaxf(v, 0.f);
    else if (act == ACT_GELU) v = 0.5f * v * (1.f + erff(v * 0.70710678118654752f));
    y[idx] = v;
}

// ---------------- xr[tb][c] = mean_n relu(bn2(raw))   (bf16 raw, BN fused)
__global__ __launch_bounds__(128) void xr2_kernel(const unsigned short* __restrict__ raw,
                                                  const float* __restrict__ stats,
                                                  const float* __restrict__ g,
                                                  const float* __restrict__ b,
                                                  float* __restrict__ xr) {
    int t = blockIdx.x / B_, bb = blockIdx.x % B_;
    const unsigned short* base = raw + ((long)bb * T_ + t) * N_ * C_;
    int c = threadIdx.x;
    float m = stats[c] * (1.f / (float)RB_);
    float var = fmaxf(stats[128 + c] * (1.f / (float)RB_) - m * m, 0.f);
    float sc = g[c] / sqrtf(var + 1e-5f);
    float sh = b[c] - m * sc;
    float s = 0.f;
    for (int n = 0; n < N_; n++) s += fmaxf(fmaf(bf2f(base[n * C_ + c]), sc, sh), 0.f);
    xr[(long)blockIdx.x * C_ + c] = s * (1.f / 200.f);
}

// ---------------- hr[tb][c] = mean_n relu(bn2(raw)) * ga[tb][n]  (bf16 raw)
__global__ __launch_bounds__(128) void hr2_kernel(const unsigned short* __restrict__ raw,
                                                  const float* __restrict__ stats,
                                                  const float* __restrict__ g,
                                                  const float* __restrict__ b,
                                                  const float* __restrict__ ga,
                                                  float* __restrict__ hr) {
    __shared__ float sga[N_];
    int t = blockIdx.x / B_, bb = blockIdx.x % B_;
    const unsigned short* base = raw + ((long)bb * T_ + t) * N_ * C_;
    for (int i = threadIdx.x; i < N_; i += blockDim.x) sga[i] = ga[(long)blockIdx.x * N_ + i];
    __syncthreads();
    int c = threadIdx.x;
    float m = stats[c] * (1.f / (float)RB_);
    float var = fmaxf(stats[128 + c] * (1.f / (float)RB_) - m * m, 0.f);
    float sc = g[c] / sqrtf(var + 1e-5f);
    float sh = b[c] - m * sc;
    float s = 0.f;
    for (int n = 0; n < N_; n++)
        s = fmaf(fmaxf(fmaf(bf2f(base[n * C_ + c]), sc, sh), 0.f), sga[n], s);
    hr[(long)blockIdx.x * C_ + c] = s * (1.f / 200.f);
}

// ---------------- generic small (R x K) @ (K x Cout) + bias, blockDim == Cout
template<int K, int ROWS>
__global__ void mm_kernel(const float* __restrict__ x, const float* __restrict__ w,
                          const float* __restrict__ bias, float* __restrict__ y,
                          int Cout, int act) {
    __shared__ float sx[ROWS * K];
    long r0 = (long)blockIdx.x * ROWS;
    for (int idx = threadIdx.x; idx < ROWS * K; idx += blockDim.x)
        sx[idx] = x[r0 * K + idx];
    __syncthreads();
    int c = threadIdx.x;
    float acc[ROWS];
    #pragma unroll
    for (int i = 0; i < ROWS; i++) acc[i] = 0.f;
    for (int k = 0; k < K; k++) {
        float wv = w[k * Cout + c];
        #pragma unroll
        for (int i = 0; i < ROWS; i++) acc[i] = fmaf(sx[i * K + k], wv, acc[i]);
    }
    float bv = bias ? bias[c] : 0.f;
    for (int i = 0; i < ROWS; i++) {
        float vv = acc[i] + bv;
        if (act == ACT_RELU) vv = fmaxf(vv, 0.f);
        y[(r0 + i) * Cout + c] = vv;
    }
}

// ---------------- ga = sigmoid(e @ aw + ab), write ws (t,b,n) and node_attn (b,l,t,n)
__global__ void ga_kernel(const float* __restrict__ e, const float* __restrict__ aw,
                          const float* __restrict__ ab, float* __restrict__ ga,
                          float* __restrict__ node_out, int l) {
    __shared__ float sx[8 * C_];
    long r0 = (long)blockIdx.x * 8;
    for (int idx = threadIdx.x; idx < 8 * C_; idx += blockDim.x)
        sx[idx] = e[r0 * C_ + idx];
    __syncthreads();
    int c = threadIdx.x;
    if (c < N_) {
        float acc[8] = {0.f,0.f,0.f,0.f,0.f,0.f,0.f,0.f};
        for (int k = 0; k < C_; k++) {
            float wv = aw[k * N_ + c];
            #pragma unroll
            for (int i = 0; i < 8; i++) acc[i] = fmaf(sx[i * C_ + k], wv, acc[i]);
        }
        float bv = ab[c];
        for (int i = 0; i < 8; i++) {
            int tb = (int)r0 + i;
            int t = tb / B_, b = tb % B_;
            float v = 1.f / (1.f + expf(-(acc[i] + bv)));
            ga[(long)tb * N_ + c] = v;
            node_out[(((long)b * L_ + l) * T_ + t) * N_ + c] = v;
        }
    }
}

// ---------------- attention scores + softmax over s; write time_attn (b,l,t,s)
__global__ void attn_kernel(const float* __restrict__ qkv, float* __restrict__ time_out, int l) {
    __shared__ float q[C_];
    int b = blockIdx.x / T_, t = blockIdx.x % T_;
    int tid = threadIdx.x;  // 64 threads = 1 wave; tid = s
    for (int idx = tid; idx < C_; idx += 64) q[idx] = qkv[((long)t * B_ + b) * 384 + idx];
    __syncthreads();
    const float* krow = qkv + ((long)tid * B_ + b) * 384 + C_;
    float s = 0.f;
    for (int c = 0; c < C_; c++) s = fmaf(q[c], krow[c], s);
    s *= 0.08838834764831843f;
    float mx = s;
    #pragma unroll
    for (int off = 32; off; off >>= 1) mx = fmaxf(mx, __shfl_xor(mx, off));
    float e = expf(s - mx), sum = e;
    #pragma unroll
    for (int off = 32; off; off >>= 1) sum += __shfl_xor(sum, off);
    time_out[(((long)b * L_ + l) * T_ + t) * T_ + tid] = e / sum;
}

// ---------------- attv[tb][c] = sum_s A[b][t][s] * v[s][b][c]
__global__ void attv_kernel(const float* __restrict__ A, const float* __restrict__ qkv,
                            float* __restrict__ attv, int l) {
    __shared__ float sa[T_];
    int t = blockIdx.x / B_, b = blockIdx.x % B_;
    for (int i = threadIdx.x; i < T_; i += blockDim.x)
        sa[i] = A[(((long)b * L_ + l) * T_ + t) * T_ + i];
    __syncthreads();
    int c = threadIdx.x;
    float s = 0.f;
    for (int sp = 0; sp < T_; sp++) s = fmaf(sa[sp], qkv[((long)sp * B_ + b) * 384 + 256 + c], s);
    attv[(long)blockIdx.x * C_ + c] = s;
}

// ---------------- LayerNorm over last dim (C_), optional residual add
__global__ void ln_kernel(const float* __restrict__ x, const float* __restrict__ x2,
                          const float* __restrict__ g, const float* __restrict__ b,
                          float* __restrict__ out) {
    __shared__ float red[C_];
    int r = blockIdx.x, c = threadIdx.x;
    float v = x[(long)r * C_ + c];
    if (x2) v += x2[(long)r * C_ + c];
    red[c] = v; __syncthreads();
    for (int off = 64; off; off >>= 1) { if (c < off) red[c] += red[c + off]; __syncthreads(); }
    float m = red[0] * (1.f / C_); __syncthreads();
    float d = v - m;
    red[c] = d * d; __syncthreads();
    for (int off = 64; off; off >>= 1) { if (c < off) red[c] += red[c + off]; __syncthreads(); }
    float var = red[0] * (1.f / C_);
    out[(long)r * C_ + c] = d * (1.f / sqrtf(var + 1e-5f)) * g[c] + b[c];
}

// ---------------- lat[b][c] = sum_t x2[tb][c]
__global__ void latsum_kernel(const float* __restrict__ x2, float* __restrict__ lat) {
    int b = blockIdx.x, c = threadIdx.x;
    float s = 0.f;
    for (int t = 0; t < T_; t++) s += x2[((long)t * B_ + b) * C_ + c];
    lat[(long)b * C_ + c] = s;
}

// ---------------- logit + feat_fMRI
__global__ void final_kernel(const float* __restrict__ lat, const float* __restrict__ cls_w,
                             const float* __restrict__ cls_b, float* __restrict__ out) {
    int idx = blockIdx.x * blockDim.x + threadIdx.x;
    if (idx < B_ * NC_) {
        int b = idx / NC_, nc = idx % NC_;
        float s = 0.f;
        for (int l = 0; l < L_; l++) {
            float acc = 0.f;
            for (int c = 0; c < C_; c++)
                acc = fmaf(lat[l * B_ * C_ + b * C_ + c], cls_w[l * C_ * NC_ + c * NC_ + nc], acc);
            s += acc + cls_b[l * NC_ + nc];
        }
        out[idx] = s;
    } else if (idx < B_ * NC_ + B_ * C_) {
        int j = idx - B_ * NC_;
        out[idx] = 0.5f * (lat[j] + lat[B_ * C_ + j]);
    }
}

// ---------------- feat_sMRI = bn(trad @ smri_w + smri_b) over batch of 8
__global__ void smri_kernel(const float* __restrict__ trad, const float* __restrict__ w,
                            const float* __restrict__ bias, const float* __restrict__ g,
                            const float* __restrict__ bb, float* __restrict__ out) {
    int c = threadIdx.x;
    float y[B_];
    for (int b = 0; b < B_; b++) {
        float s = bias[c];
        for (int k = 0; k < S_; k++) s = fmaf(trad[b * S_ + k], w[k * C_ + c], s);
        y[b] = s;
    }
    float m = 0.f;
    for (int b = 0; b < B_; b++) m += y[b];
    m *= (1.f / B_);
    float var = 0.f;
    for (int b = 0; b < B_; b++) { float d = y[b] - m; var += d * d; }
    var *= (1.f / B_);
    float inv = 1.f / sqrtf(var + 1e-5f);
    for (int b = 0; b < B_; b++) out[b * C_ + c] = (y[b] - m) * inv * g[c] + bb[c];
}

// ============================================================================
extern "C" void kernel_launch(void* const* d_in, const int* in_sizes, int n_in,
                              void* d_out, int out_size, void* d_ws, size_t ws_size,
                              hipStream_t stream) {
    const float* fv       = (const float*)d_in[0];
    const float* fa       = (const float*)d_in[1];
    const float* trad     = (const float*)d_in[2];
    const float* w_init   = (const float*)d_in[6];
    const float* b_init   = (const float*)d_in[7];
    const float* gin_eps  = (const float*)d_in[8];
    const float* gin_w1   = (const float*)d_in[9];
    const float* gin_b1   = (const float*)d_in[10];
    const float* gbn1g    = (const float*)d_in[11];
    const float* gbn1b    = (const float*)d_in[12];
    const float* gin_w2   = (const float*)d_in[13];
    const float* gin_b2   = (const float*)d_in[14];
    const float* gbn2g    = (const float*)d_in[15];
    const float* gbn2b    = (const float*)d_in[16];
    const float* sero_w   = (const float*)d_in[17];
    const float* sero_b   = (const float*)d_in[18];
    const float* sbng     = (const float*)d_in[19];
    const float* sbnb     = (const float*)d_in[20];
    const float* sero_aw  = (const float*)d_in[21];
    const float* sero_ab  = (const float*)d_in[22];
    const float* wqkv     = (const float*)d_in[23];
    const float* bqkv     = (const float*)d_in[24];
    const float* wo       = (const float*)d_in[25];
    const float* bo       = (const float*)d_in[26];
    const float* ln1g     = (const float*)d_in[27];
    const float* ln1b     = (const float*)d_in[28];
    const float* ln2g     = (const float*)d_in[29];
    const float* ln2b     = (const float*)d_in[30];
    const float* tw1      = (const float*)d_in[31];
    const float* tb1      = (const float*)d_in[32];
    const float* tw2      = (const float*)d_in[33];
    const float* tb2      = (const float*)d_in[34];
    const float* cls_w    = (const float*)d_in[35];
    const float* cls_b    = (const float*)d_in[36];
    const float* smri_w   = (const float*)d_in[37];
    const float* smri_b   = (const float*)d_in[38];
    const float* smri_g   = (const float*)d_in[39];
    const float* smri_bb  = (const float*)d_in[40];

    float* out = (float*)d_out;

    // workspace layout
    const long SZ_BIG = (long)RB_ * C_;            // 13,107,200 elements
    unsigned short* H3b = (unsigned short*)d_ws;   // bf16 big buffers
    unsigned short* Y1b = H3b + SZ_BIG;
    unsigned short* Y2b = Y1b + SZ_BIG;
    float* fbase = (float*)(Y2b + SZ_BIG);
    float* THR  = fbase;                  // 512
    float* STAT = THR + 512;              // 256
    float* XR   = STAT + 256;             // 512*128
    float* E    = XR  + BT_ * C_;
    float* GA   = E   + BT_ * C_;         // 512*200
    float* HR   = GA  + BT_ * N_;
    float* QKV  = HR  + BT_ * C_;         // 512*384
    float* ATTV = QKV + BT_ * 3 * C_;
    float* ATT  = ATTV + BT_ * C_;
    float* X1   = ATT + BT_ * C_;
    float* MMB  = X1  + BT_ * C_;         // 512*256 (FFN scratch)
    float* X2   = MMB + BT_ * 2 * C_;
    float* LAT  = X2  + BT_ * C_;         // 2*8*128
    float* STATB = MMB;   // overlay: BN2 stats; lifetime disjoint from FFN scratch
    unsigned short* WT0 = (unsigned short*)(LAT + L_ * B_ * C_);  // w_init^T: 128 x 224
    unsigned short* WT1 = WT0 + 128 * 224;                        // gin_w1^T: 2 x (128x128)
    unsigned short* WT2 = WT1 + 2 * 128 * 128;                    // gin_w2^T: 2 x (128x128)

    // output layout (floats)
    float* OUT_LOGIT = out;            // 16 logit + 1024 feat_fMRI
    float* OUT_FEATS = out + 1040;     // 1024 (feat_sMRI)
    float* OUT_NODE  = out + 2064;     // 204800
    float* OUT_TIME  = out + 206864;   // 65536

    // ---- one-shot weight transpose+cvt (tiny)
    wtcvt_kernel<<<128, 64, 0, stream>>>(w_init, 200, 224, WT0);
    wtcvt_kernel<<<128, 64, 0, stream>>>(gin_w1,           128, 128, WT1);
    wtcvt_kernel<<<128, 64, 0, stream>>>(gin_w1 + C_ * C_, 128, 128, WT1 + 128 * 128);
    wtcvt_kernel<<<128, 64, 0, stream>>>(gin_w2,           128, 128, WT2);
    wtcvt_kernel<<<128, 64, 0, stream>>>(gin_w2 + C_ * C_, 128, 128, WT2 + 128 * 128);

    // h3 = fv @ w_init + b_init   (fp32 in, bf16 out)
    mfma_mm_kernel<false, false, true><<<RB_ / 128, 256, 0, stream>>>(
        fv, 200, 200, WT0, 224, b_init, nullptr, nullptr, nullptr, H3b);
    thr_kernel<<<BT_, 512, 0, stream>>>(fa, THR);

    for (int l = 0; l < L_; l++) {
        // zh = h3 @ w1 (bf16 in/out); y2 = (mask + eps I)@zh + b1 (MFMA)
        mfma_mm_kernel<true, false, false><<<RB_ / 128, 256, 0, stream>>>(
            H3b, 128, 128, WT1 + l * 128 * 128, 128, nullptr, nullptr, nullptr, nullptr, Y1b);
        maskagg_mfma_kernel<<<BT_, 256, 0, stream>>>(fa, THR, Y1b, gin_eps, l, gin_b1 + l * C_, Y2b);
        hipMemsetAsync(STAT, 0, 256 * sizeof(float), stream);
        colstats_bf16_kernel<<<RB_ / 256, 256, 0, stream>>>(Y2b, 256, RB_, STAT);
        // Y1raw = relu(bn1(Y2)) @ w2 + b2   (BN+relu fused into staging)
        mfma_mm_kernel<true, true, true><<<RB_ / 128, 256, 0, stream>>>(
            Y2b, 128, 128, WT2 + l * 128 * 128, 128, gin_b2 + l * C_, STAT,
            gbn1g + l * C_, gbn1b + l * C_, Y1b);
        hipMemsetAsync(STATB, 0, 256 * sizeof(float), stream);
        colstats_bf16_kernel<<<RB_ / 256, 256, 0, stream>>>(Y1b, 256, RB_, STATB);
        // hb = relu(bn2(Y1raw)) applied on-the-fly in xr2/hr2
        xr2_kernel<<<BT_, 128, 0, stream>>>(Y1b, STATB, gbn2g + l * C_, gbn2b + l * C_, XR);

        mm_kernel<128, 8><<<BT_ / 8, 128, 0, stream>>>(XR, sero_w + l * C_ * C_, sero_b + l * C_, E, C_, ACT_NONE);
        hipMemsetAsync(STAT, 0, 256 * sizeof(float), stream);
        colstats_kernel<<<2, 256, 0, stream>>>(E, 256, BT_, STAT);
        bnact_kernel<<<(BT_ * C_) / 256, 256, 0, stream>>>(E, BT_, STAT, sbng + l * C_, sbnb + l * C_, ACT_GELU);

        ga_kernel<<<BT_ / 8, 256, 0, stream>>>(E, sero_aw + l * C_ * N_, sero_ab + l * N_, GA, OUT_NODE, l);
        hr2_kernel<<<BT_, 128, 0, stream>>>(Y1b, STATB, gbn2g + l * C_, gbn2b + l * C_, GA, HR);

        mm_kernel<128, 8><<<BT_ / 8, 384, 0, stream>>>(HR, wqkv + l * C_ * 3 * C_, bqkv + l * 3 * C_, QKV, 3 * C_, ACT_NONE);
        attn_kernel<<<B_ * T_, 64, 0, stream>>>(QKV, OUT_TIME, l);
        attv_kernel<<<BT_, 128, 0, stream>>>(OUT_TIME, QKV, ATTV, l);
        mm_kernel<128, 8><<<BT_ / 8, 128, 0, stream>>>(ATTV, wo + l * C_ * C_, bo + l * C_, ATT, C_, ACT_NONE);
        ln_kernel<<<BT_, 128, 0, stream>>>(ATT, nullptr, ln1g + l * C_, ln1b + l * C_, X1);
        mm_kernel<128, 8><<<BT_ / 8, 256, 0, stream>>>(X1, tw1 + l * C_ * 2 * C_, tb1 + l * 2 * C_, MMB, 2 * C_, ACT_RELU);
        mm_kernel<256, 8><<<BT_ / 8, 128, 0, stream>>>(MMB, tw2 + l * 2 * C_ * C_, tb2 + l * C_, ATTV, C_, ACT_NONE);
        ln_kernel<<<BT_, 128, 0, stream>>>(X1, ATTV, ln2g + l * C_, ln2b + l * C_, X2);
        latsum_kernel<<<B_, 128, 0, stream>>>(X2, LAT + l * B_ * C_);
    }

    final_kernel<<<5, 256, 0, stream>>>(LAT, cls_w, cls_b, OUT_LOGIT);
    smri_kernel<<<1, 128, 0, stream>>>(trad, smri_w, smri_b, smri_g, smri_bb, OUT_FEATS);
}

// Round 6
// 1083.154 us; speedup vs baseline: 1.3419x; 1.3102x over previous
//
#include <hip/hip_runtime.h>
#include <math.h>

// Problem dims
#define B_   8
#define T_   64
#define N_   200
#define CIN_ 200
#define C_   128
#define L_   2
#define NC_  2
#define S_   100
#define BT_  512      // B*T
#define RB_  102400   // B*T*N

#define ACT_NONE 0
#define ACT_RELU 1
#define ACT_GELU 2

typedef __attribute__((ext_vector_type(8))) short short8v;
typedef __attribute__((ext_vector_type(4))) float f32x4v;

union U4S8 { uint4 u; short8v s; };

__device__ __forceinline__ unsigned short f2bf(float f) {
    unsigned u = __float_as_uint(f);
    unsigned r = (u + 0x7FFFu + ((u >> 16) & 1u)) >> 16;   // RNE
    return (unsigned short)r;
}
__device__ __forceinline__ float bf2f(unsigned short u) {
    return __uint_as_float(((unsigned)u) << 16);
}
__device__ __forceinline__ float bflo(unsigned u) { return __uint_as_float(u << 16); }
__device__ __forceinline__ float bfhi(unsigned u) { return __uint_as_float(u & 0xFFFF0000u); }
__device__ __forceinline__ unsigned packbf(float a, float b) {
    return (unsigned)f2bf(a) | ((unsigned)f2bf(b) << 16);
}

// ============================================================================
// thr_kernel v3: per-(b,t) 70th percentile + packed edge bitmask (200x7 words)
__device__ __forceinline__ void thr_process(float v, int lane, int& c_lo,
                                            int* s_cnt, float* cand, int* hist) {
    bool isc = false;
    if (v < 0.65f) {
        c_lo++;
    } else if (v < 0.75f) {
        isc = true;
        int bin = (int)((v - 0.65f) * 10240.0f);
        bin = bin < 0 ? 0 : (bin > 1023 ? 1023 : bin);
        atomicAdd(&hist[bin], 1);
    }
    unsigned long long mk = __ballot(isc);
    if (mk) {
        int ldr = __ffsll((unsigned long long)mk) - 1;
        int base = 0;
        if (lane == ldr) base = atomicAdd(s_cnt, __popcll(mk));
        base = __shfl(base, ldr);
        if (isc) {
            int p = base + __popcll(mk & ((1ull << lane) - 1ull));
            if (p < 6144) cand[p] = v;
        }
    }
}

__global__ __launch_bounds__(512) void thr_kernel(const float* __restrict__ a,
                                                  float* __restrict__ thr,
                                                  unsigned* __restrict__ msk) {
    __shared__ int   hist[1024];
    __shared__ float cand[6144];
    __shared__ int   red[512];
    __shared__ int   part[256];
    __shared__ int   grp[32];
    __shared__ float cand2[256];
    __shared__ int   meta[8];
    __shared__ float s_thr;
    int tid = threadIdx.x, lane = tid & 63;
    int bt = blockIdx.x;
    for (int i = tid; i < 1024; i += 512) hist[i] = 0;
    if (tid == 0) { meta[0] = 0; meta[1] = 0; }
    __syncthreads();

    const float4* x4 = (const float4*)(a + (long)bt * 40000);
    int c_lo = 0;
    for (int i4 = tid; i4 < 10000; i4 += 512) {
        float4 v = x4[i4];
        thr_process(v.x, lane, c_lo, &meta[0], cand, hist);
        thr_process(v.y, lane, c_lo, &meta[0], cand, hist);
        thr_process(v.z, lane, c_lo, &meta[0], cand, hist);
        thr_process(v.w, lane, c_lo, &meta[0], cand, hist);
    }
    red[tid] = c_lo;
    __syncthreads();
    for (int off = 256; off; off >>= 1) {
        if (tid < off) red[tid] += red[tid + off];
        __syncthreads();
    }
    int c_lo_tot = red[0];
    if (tid < 256) part[tid] = hist[4*tid] + hist[4*tid+1] + hist[4*tid+2] + hist[4*tid+3];
    __syncthreads();
    if (tid < 32) {
        int s = 0;
        for (int i = 0; i < 8; i++) s += part[8*tid + i];
        grp[tid] = s;
    }
    __syncthreads();
    if (tid == 0) {
        int r = 27999 - c_lo_tot;
        int cum = 0, g = 0;
        while (cum + grp[g] <= r) cum += grp[g++];
        int t = g * 8;
        while (cum + part[t] <= r) cum += part[t++];
        int b = t * 4;
        while (cum + hist[b] <= r) cum += hist[b++];
        meta[2] = b; meta[3] = cum;
        int r1 = r + 1;
        cum = 0; g = 0;
        while (cum + grp[g] <= r1) cum += grp[g++];
        t = g * 8;
        while (cum + part[t] <= r1) cum += part[t++];
        b = t * 4;
        while (cum + hist[b] <= r1) cum += hist[b++];
        meta[4] = b; meta[5] = r;
    }
    __syncthreads();
    int blo = meta[2], base = meta[3], bhi = meta[4], r = meta[5];
    int m = meta[0]; if (m > 6144) m = 6144;
    for (int i = tid; i < m; i += 512) {
        float v = cand[i];
        int bin = (int)((v - 0.65f) * 10240.0f);
        bin = bin < 0 ? 0 : (bin > 1023 ? 1023 : bin);
        if (bin >= blo && bin <= bhi) {
            int p = atomicAdd(&meta[1], 1);
            if (p < 256) cand2[p] = v;
        }
    }
    __syncthreads();
    if (tid == 0) {
        int m2 = meta[1]; if (m2 > 256) m2 = 256;
        for (int i = 1; i < m2; i++) {
            float key = cand2[i]; int j = i - 1;
            while (j >= 0 && cand2[j] > key) { cand2[j+1] = cand2[j]; j--; }
            cand2[j+1] = key;
        }
        float s1 = cand2[r - base], s2 = cand2[r + 1 - base];
        float tv = s1 * 0.701171875f + s2 * 0.298828125f;
        thr[bt] = tv;
        s_thr = tv;
    }
    __syncthreads();
    // ---- pass 2: pack bitmask (fa is L3-resident). word w of row i = cols w*32..
    float tv = s_thr;
    const float* abase = a + (long)bt * 40000;
    for (int idx = tid; idx < 1400; idx += 512) {
        int row = idx / 7, w = idx - row * 7;
        const float* p = abase + row * 200 + w * 32;
        int nv = (w == 6) ? 8 : 32;
        unsigned bits = 0u;
        for (int j = 0; j < nv; j += 4) {
            float4 v = *(const float4*)&p[j];
            bits |= (v.x > tv ? 1u : 0u) << j;
            bits |= (v.y > tv ? 1u : 0u) << (j + 1);
            bits |= (v.z > tv ? 1u : 0u) << (j + 2);
            bits |= (v.w > tv ? 1u : 0u) << (j + 3);
        }
        msk[(long)bt * 1400 + idx] = bits;
    }
}

// ============================================================================
// wtcvt: weight (K x 128) fp32 -> wt (128 x Kpad) bf16, k-contiguous, zero-padded
__global__ void wtcvt_kernel(const float* __restrict__ w, int K, int Kpad,
                             unsigned short* __restrict__ wt) {
    int c = blockIdx.x;                    // 128 blocks
    for (int k = threadIdx.x; k < Kpad; k += 64) {
        float v = (k < K) ? w[(long)k * 128 + c] : 0.f;
        wt[(long)c * Kpad + k] = f2bf(v);
    }
}

// ============================================================================
// gemm_direct: (102400 x K) @ wt(128 x Kpad bf16) -> y bf16, NO LDS staging.
// A-frags and B-frags loaded directly from global (16B/lane, coalesced).
// Optional fused input-BN+ReLU (bf16 path) and fused output column stats.
template<bool A_BF16, bool BN_IN, bool BIAS_OUT, bool STATS_OUT>
__global__ __launch_bounds__(256) void gemm_direct_kernel(
        const void* __restrict__ xv, int K, int Kstride, int Ksteps,
        const unsigned short* __restrict__ wt, int Kpad,
        const float* __restrict__ bias, const float* __restrict__ statsIn,
        const float* __restrict__ bng, const float* __restrict__ bnb,
        unsigned short* __restrict__ y, float* __restrict__ statsOut) {
    __shared__ float bnS[128], bnB[128];
    __shared__ float redS[2048], redQ[2048];
    int tid = threadIdx.x;
    if (BN_IN) {
        if (tid < 128) {
            float mm = statsIn[tid] * (1.f / (float)RB_);
            float var = fmaxf(statsIn[128 + tid] * (1.f / (float)RB_) - mm * mm, 0.f);
            float sc = bng[tid] / sqrtf(var + 1e-5f);
            bnS[tid] = sc; bnB[tid] = bnb[tid] - mm * sc;
        }
        __syncthreads();
    }
    int wave = tid >> 6, lane = tid & 63, quad = lane >> 4, m16 = lane & 15;
    long rowA = (long)blockIdx.x * 128 + wave * 32;

    f32x4v acc[2][8];
    #pragma unroll
    for (int i = 0; i < 2; i++)
        #pragma unroll
        for (int j = 0; j < 8; j++) acc[i][j] = (f32x4v){0.f, 0.f, 0.f, 0.f};

    for (int ks = 0; ks < Ksteps; ks++) {
        int kf = ks * 32 + quad * 8;        // this lane's fragment k-start
        // ---- B fragments (weights: L1/L2 resident)
        U4S8 bU[8];
        #pragma unroll
        for (int nt = 0; nt < 8; nt++)
            bU[nt].u = *(const uint4*)&wt[(long)(nt * 16 + m16) * Kpad + kf];
        // ---- A fragments
        U4S8 aU[2];
        if (A_BF16) {
            const unsigned short* xb = (const unsigned short*)xv;
            #pragma unroll
            for (int mt = 0; mt < 2; mt++)
                aU[mt].u = *(const uint4*)&xb[(rowA + mt * 16 + m16) * Kstride + kf];
            if (BN_IN) {
                float4 s0 = *(const float4*)&bnS[kf], s1 = *(const float4*)&bnS[kf + 4];
                float4 b0 = *(const float4*)&bnB[kf], b1 = *(const float4*)&bnB[kf + 4];
                #pragma unroll
                for (int mt = 0; mt < 2; mt++) {
                    uint4 u = aU[mt].u;
                    float f0 = fmaxf(bflo(u.x) * s0.x + b0.x, 0.f);
                    float f1 = fmaxf(bfhi(u.x) * s0.y + b0.y, 0.f);
                    float f2 = fmaxf(bflo(u.y) * s0.z + b0.z, 0.f);
                    float f3 = fmaxf(bfhi(u.y) * s0.w + b0.w, 0.f);
                    float f4 = fmaxf(bflo(u.z) * s1.x + b1.x, 0.f);
                    float f5 = fmaxf(bfhi(u.z) * s1.y + b1.y, 0.f);
                    float f6 = fmaxf(bflo(u.w) * s1.z + b1.z, 0.f);
                    float f7 = fmaxf(bfhi(u.w) * s1.w + b1.w, 0.f);
                    u.x = packbf(f0, f1); u.y = packbf(f2, f3);
                    u.z = packbf(f4, f5); u.w = packbf(f6, f7);
                    aU[mt].u = u;
                }
            }
        } else {
            const float* x = (const float*)xv;
            #pragma unroll
            for (int mt = 0; mt < 2; mt++) {
                uint4 o = {0u, 0u, 0u, 0u};
                if (kf + 8 <= K) {          // K % 8 == 0 here, so all-or-nothing
                    const float* p = &x[(rowA + mt * 16 + m16) * Kstride + kf];
                    float4 v0 = *(const float4*)p;
                    float4 v1 = *(const float4*)(p + 4);
                    o.x = packbf(v0.x, v0.y); o.y = packbf(v0.z, v0.w);
                    o.z = packbf(v1.x, v1.y); o.w = packbf(v1.z, v1.w);
                }
                aU[mt].u = o;
            }
        }
        // ---- MFMA
        #pragma unroll
        for (int nt = 0; nt < 8; nt++) {
            acc[0][nt] = __builtin_amdgcn_mfma_f32_16x16x32_bf16(aU[0].s, bU[nt].s, acc[0][nt], 0, 0, 0);
            acc[1][nt] = __builtin_amdgcn_mfma_f32_16x16x32_bf16(aU[1].s, bU[nt].s, acc[1][nt], 0, 0, 0);
        }
    }
    // ---- epilogue
    float sAcc[8], qAcc[8];
    #pragma unroll
    for (int nt = 0; nt < 8; nt++) {
        int col = nt * 16 + m16;
        float bv = BIAS_OUT ? bias[col] : 0.f;
        float s = 0.f, q = 0.f;
        #pragma unroll
        for (int mt = 0; mt < 2; mt++) {
            long row = rowA + mt * 16 + quad * 4;
            #pragma unroll
            for (int i = 0; i < 4; i++) {
                float v = acc[mt][nt][i] + bv;
                y[(row + i) * 128 + col] = f2bf(v);
                if (STATS_OUT) { s += v; q += v * v; }
            }
        }
        sAcc[nt] = s; qAcc[nt] = q;
    }
    if (STATS_OUT) {
        #pragma unroll
        for (int nt = 0; nt < 8; nt++) {
            int col = nt * 16 + m16;
            redS[col * 16 + wave * 4 + quad] = sAcc[nt];
            redQ[col * 16 + wave * 4 + quad] = qAcc[nt];
        }
        __syncthreads();
        if (tid < 128) {
            float s = 0.f, q = 0.f;
            #pragma unroll
            for (int j = 0; j < 16; j++) { s += redS[tid * 16 + j]; q += redQ[tid * 16 + j]; }
            atomicAdd(&statsOut[tid], s);
            atomicAdd(&statsOut[128 + tid], q);
        }
    }
}

// ============================================================================
// zt: zh (per bt, 200x128 bf16 row-major) -> zh^T (128 x 224 bf16, zero-padded)
__global__ __launch_bounds__(256) void zt_kernel(const unsigned short* __restrict__ zh,
                                                 unsigned short* __restrict__ zt) {
    __shared__ unsigned short tile[200 * 136];
    int tid = threadIdx.x;
    int bt = blockIdx.x;
    const unsigned short* src = zh + (long)bt * N_ * C_;
    for (int idx = tid; idx < 3200; idx += 256) {          // 200 rows x 16 uint4
        int r = idx >> 4, c8 = (idx & 15) << 3;
        *(uint4*)&tile[r * 136 + c8] = *(const uint4*)&src[r * C_ + c8];
    }
    __syncthreads();
    unsigned short* dst = zt + (long)bt * 128 * 224;
    int c = tid & 127, kh = tid >> 7;                       // 128 cols x 2 k-halves
    for (int u = 0; u < 14; u++) {
        int k0 = kh * 112 + u * 8;
        uint4 o;
        unsigned short e[8];
        #pragma unroll
        for (int j = 0; j < 8; j++)
            e[j] = (k0 + j < N_) ? tile[(k0 + j) * 136 + c] : (unsigned short)0;
        o.x = (unsigned)e[0] | ((unsigned)e[1] << 16);
        o.y = (unsigned)e[2] | ((unsigned)e[3] << 16);
        o.z = (unsigned)e[4] | ((unsigned)e[5] << 16);
        o.w = (unsigned)e[6] | ((unsigned)e[7] << 16);
        *(uint4*)&dst[c * 224 + k0] = o;
    }
}

// ============================================================================
// maskagg v6: y2 = (mask + eps*I) @ zh + b1, bf16. NO LDS staging, NO k-loop
// barriers. A-frags expanded from packed bitmask in registers; B-frags read
// directly from zh^T (L2-resident). 1024 blocks (2 per bt x 128 rows).
// Fused column stats (for BN1) -> statsOut.
__global__ __launch_bounds__(256) void maskagg_kernel(
        const unsigned* __restrict__ msk, const unsigned short* __restrict__ zt,
        const float* __restrict__ geps, int l, const float* __restrict__ b1,
        unsigned short* __restrict__ y, float* __restrict__ statsOut) {
    __shared__ unsigned sbits[128 * 7];
    __shared__ float redS[2048], redQ[2048];
    int tid = threadIdx.x;
    int bt = blockIdx.x >> 1, half = blockIdx.x & 1;
    int row0 = half * 128;
    for (int idx = tid; idx < 896; idx += 256) {
        int gr = row0 + idx / 7;
        sbits[idx] = (gr < N_) ? msk[(long)bt * 1400 + gr * 7 + (idx % 7)] : 0u;
    }
    __syncthreads();
    float eps = geps[l];
    unsigned ONEu = 0x3F80u;
    unsigned E0 = (unsigned)f2bf(eps), E1 = (unsigned)f2bf(1.f + eps);
    int wave = tid >> 6, lane = tid & 63, quad = lane >> 4, m16 = lane & 15;
    const unsigned short* ztb = zt + (long)bt * 128 * 224;

    f32x4v acc[2][8];
    #pragma unroll
    for (int i = 0; i < 2; i++)
        #pragma unroll
        for (int j = 0; j < 8; j++) acc[i][j] = (f32x4v){0.f, 0.f, 0.f, 0.f};

    for (int kc = 0; kc < 7; kc++) {
        int kf = kc * 32 + quad * 8;
        // ---- B fragments from zh^T (contiguous 16B per lane)
        U4S8 bU[8];
        #pragma unroll
        for (int nt = 0; nt < 8; nt++)
            bU[nt].u = *(const uint4*)&ztb[(nt * 16 + m16) * 224 + kf];
        // ---- A fragments from bitmask (registers only)
        U4S8 aU[2];
        #pragma unroll
        for (int mt = 0; mt < 2; mt++) {
            int lr = wave * 32 + mt * 16 + m16;
            unsigned bits = (sbits[lr * 7 + kc] >> (quad * 8)) & 0xFFu;
            int gr = row0 + lr;
            unsigned o[4];
            #pragma unroll
            for (int p = 0; p < 4; p++) {
                int j0 = 2 * p, j1 = 2 * p + 1;
                unsigned lo = ((bits >> j0) & 1u) ? ONEu : 0u;
                unsigned hi = ((bits >> j1) & 1u) ? ONEu : 0u;
                if (gr == kf + j0) lo = ((bits >> j0) & 1u) ? E1 : E0;
                if (gr == kf + j1) hi = ((bits >> j1) & 1u) ? E1 : E0;
                o[p] = lo | (hi << 16);
            }
            aU[mt].u = make_uint4(o[0], o[1], o[2], o[3]);
        }
        // ---- MFMA
        #pragma unroll
        for (int nt = 0; nt < 8; nt++) {
            acc[0][nt] = __builtin_amdgcn_mfma_f32_16x16x32_bf16(aU[0].s, bU[nt].s, acc[0][nt], 0, 0, 0);
            acc[1][nt] = __builtin_amdgcn_mfma_f32_16x16x32_bf16(aU[1].s, bU[nt].s, acc[1][nt], 0, 0, 0);
        }
    }
    // ---- epilogue: +b1, store rows<200, fused stats
    float sAcc[8], qAcc[8];
    #pragma unroll
    for (int nt = 0; nt < 8; nt++) {
        int col = nt * 16 + m16;
        float bv = b1[col];
        float s = 0.f, q = 0.f;
        #pragma unroll
        for (int mt = 0; mt < 2; mt++) {
            int lr = wave * 32 + mt * 16 + quad * 4;
            #pragma unroll
            for (int i = 0; i < 4; i++) {
                int gr = row0 + lr + i;
                if (gr < N_) {
                    float v = acc[mt][nt][i] + bv;
                    y[((long)bt * N_ + gr) * 128 + col] = f2bf(v);
                    s += v; q += v * v;
                }
            }
        }
        sAcc[nt] = s; qAcc[nt] = q;
    }
    #pragma unroll
    for (int nt = 0; nt < 8; nt++) {
        int col = nt * 16 + m16;
        redS[col * 16 + wave * 4 + quad] = sAcc[nt];
        redQ[col * 16 + wave * 4 + quad] = qAcc[nt];
    }
    __syncthreads();
    if (tid < 128) {
        float s = 0.f, q = 0.f;
        #pragma unroll
        for (int j = 0; j < 16; j++) { s += redS[tid * 16 + j]; q += redQ[tid * 16 + j]; }
        atomicAdd(&statsOut[tid], s);
        atomicAdd(&statsOut[128 + tid], q);
    }
}

// ---------------- column sums & sumsq fp32 (small tensors)
__global__ void colstats_kernel(const float* __restrict__ y, int rows_per_block, int R,
                                float* __restrict__ stats) {
    int col = threadIdx.x & 127, sub = threadIdx.x >> 7;
    int r0 = blockIdx.x * rows_per_block;
    float s = 0.f, ss = 0.f;
    for (int r = r0 + sub; r < r0 + rows_per_block && r < R; r += 2) {
        float v = y[(long)r * C_ + col];
        s += v; ss += v * v;
    }
    atomicAdd(&stats[col], s);
    atomicAdd(&stats[C_ + col], ss);
}

// ---------------- apply BN (batch stats) + activation, in place (small tensors)
__global__ void bnact_kernel(float* __restrict__ y, int R, const float* __restrict__ stats,
                             const float* __restrict__ g, const float* __restrict__ b, int act) {
    long idx = (long)blockIdx.x * blockDim.x + threadIdx.x;
    if (idx >= (long)R * C_) return;
    int col = idx & (C_ - 1);
    float m   = stats[col] / (float)R;
    float var = fmaxf(stats[C_ + col] / (float)R - m * m, 0.f);
    float inv = 1.f / sqrtf(var + 1e-5f);
    float v = (y[idx] - m) * inv * g[col] + b[col];
    if (act == ACT_RELU)      v = fmaxf(v, 0.f);
    else if (act == ACT_GELU) v = 0.5f * v * (1.f + erff(v * 0.70710678118654752f));
    y[idx] = v;
}

// ---------------- xr[tb][c] = mean_n relu(bn2(raw))   (bf16 raw, BN fused)
__global__ __launch_bounds__(128) void xr2_kernel(const unsigned short* __restrict__ raw,
                                                  const float* __restrict__ stats,
                                                  const float* __restrict__ g,
                                                  const float* __restrict__ b,
                                                  float* __restrict__ xr) {
    int t = blockIdx.x / B_, bb = blockIdx.x % B_;
    const unsigned short* base = raw + ((long)bb * T_ + t) * N_ * C_;
    int c = threadIdx.x;
    float m = stats[c] * (1.f / (float)RB_);
    float var = fmaxf(stats[128 + c] * (1.f / (float)RB_) - m * m, 0.f);
    float sc = g[c] / sqrtf(var + 1e-5f);
    float sh = b[c] - m * sc;
    float s = 0.f;
    for (int n = 0; n < N_; n++) s += fmaxf(fmaf(bf2f(base[n * C_ + c]), sc, sh), 0.f);
    xr[(long)blockIdx.x * C_ + c] = s * (1.f / 200.f);
}

// ---------------- hr[tb][c] = mean_n relu(bn2(raw)) * ga[tb][n]  (bf16 raw)
__global__ __launch_bounds__(128) void hr2_kernel(const unsigned short* __restrict__ raw,
                                                  const float* __restrict__ stats,
                                                  const float* __restrict__ g,
                                                  const float* __restrict__ b,
                                                  const float* __restrict__ ga,
                                                  float* __restrict__ hr) {
    __shared__ float sga[N_];
    int t = blockIdx.x / B_, bb = blockIdx.x % B_;
    const unsigned short* base = raw + ((long)bb * T_ + t) * N_ * C_;
    for (int i = threadIdx.x; i < N_; i += blockDim.x) sga[i] = ga[(long)blockIdx.x * N_ + i];
    __syncthreads();
    int c = threadIdx.x;
    float m = stats[c] * (1.f / (float)RB_);
    float var = fmaxf(stats[128 + c] * (1.f / (float)RB_) - m * m, 0.f);
    float sc = g[c] / sqrtf(var + 1e-5f);
    float sh = b[c] - m * sc;
    float s = 0.f;
    for (int n = 0; n < N_; n++)
        s = fmaf(fmaxf(fmaf(bf2f(base[n * C_ + c]), sc, sh), 0.f), sga[n], s);
    hr[(long)blockIdx.x * C_ + c] = s * (1.f / 200.f);
}

// ---------------- generic small (R x K) @ (K x Cout) + bias, blockDim == Cout
template<int K, int ROWS>
__global__ void mm_kernel(const float* __restrict__ x, const float* __restrict__ w,
                          const float* __restrict__ bias, float* __restrict__ y,
                          int Cout, int act) {
    __shared__ float sx[ROWS * K];
    long r0 = (long)blockIdx.x * ROWS;
    for (int idx = threadIdx.x; idx < ROWS * K; idx += blockDim.x)
        sx[idx] = x[r0 * K + idx];
    __syncthreads();
    int c = threadIdx.x;
    float acc[ROWS];
    #pragma unroll
    for (int i = 0; i < ROWS; i++) acc[i] = 0.f;
    for (int k = 0; k < K; k++) {
        float wv = w[k * Cout + c];
        #pragma unroll
        for (int i = 0; i < ROWS; i++) acc[i] = fmaf(sx[i * K + k], wv, acc[i]);
    }
    float bv = bias ? bias[c] : 0.f;
    for (int i = 0; i < ROWS; i++) {
        float vv = acc[i] + bv;
        if (act == ACT_RELU) vv = fmaxf(vv, 0.f);
        y[(r0 + i) * Cout + c] = vv;
    }
}

// ---------------- ga = sigmoid(e @ aw + ab), write ws (t,b,n) and node_attn (b,l,t,n)
__global__ void ga_kernel(const float* __restrict__ e, const float* __restrict__ aw,
                          const float* __restrict__ ab, float* __restrict__ ga,
                          float* __restrict__ node_out, int l) {
    __shared__ float sx[8 * C_];
    long r0 = (long)blockIdx.x * 8;
    for (int idx = threadIdx.x; idx < 8 * C_; idx += blockDim.x)
        sx[idx] = e[r0 * C_ + idx];
    __syncthreads();
    int c = threadIdx.x;
    if (c < N_) {
        float acc[8] = {0.f,0.f,0.f,0.f,0.f,0.f,0.f,0.f};
        for (int k = 0; k < C_; k++) {
            float wv = aw[k * N_ + c];
            #pragma unroll
            for (int i = 0; i < 8; i++) acc[i] = fmaf(sx[i * C_ + k], wv, acc[i]);
        }
        float bv = ab[c];
        for (int i = 0; i < 8; i++) {
            int tb = (int)r0 + i;
            int t = tb / B_, b = tb % B_;
            float v = 1.f / (1.f + expf(-(acc[i] + bv)));
            ga[(long)tb * N_ + c] = v;
            node_out[(((long)b * L_ + l) * T_ + t) * N_ + c] = v;
        }
    }
}

// ---------------- attention scores + softmax over s; write time_attn (b,l,t,s)
__global__ void attn_kernel(const float* __restrict__ qkv, float* __restrict__ time_out, int l) {
    __shared__ float q[C_];
    int b = blockIdx.x / T_, t = blockIdx.x % T_;
    int tid = threadIdx.x;  // 64 threads = 1 wave; tid = s
    for (int idx = tid; idx < C_; idx += 64) q[idx] = qkv[((long)t * B_ + b) * 384 + idx];
    __syncthreads();
    const float* krow = qkv + ((long)tid * B_ + b) * 384 + C_;
    float s = 0.f;
    for (int c = 0; c < C_; c++) s = fmaf(q[c], krow[c], s);
    s *= 0.08838834764831843f;
    float mx = s;
    #pragma unroll
    for (int off = 32; off; off >>= 1) mx = fmaxf(mx, __shfl_xor(mx, off));
    float e = expf(s - mx), sum = e;
    #pragma unroll
    for (int off = 32; off; off >>= 1) sum += __shfl_xor(sum, off);
    time_out[(((long)b * L_ + l) * T_ + t) * T_ + tid] = e / sum;
}

// ---------------- attv[tb][c] = sum_s A[b][t][s] * v[s][b][c]
__global__ void attv_kernel(const float* __restrict__ A, const float* __restrict__ qkv,
                            float* __restrict__ attv, int l) {
    __shared__ float sa[T_];
    int t = blockIdx.x / B_, b = blockIdx.x % B_;
    for (int i = threadIdx.x; i < T_; i += blockDim.x)
        sa[i] = A[(((long)b * L_ + l) * T_ + t) * T_ + i];
    __syncthreads();
    int c = threadIdx.x;
    float s = 0.f;
    for (int sp = 0; sp < T_; sp++) s = fmaf(sa[sp], qkv[((long)sp * B_ + b) * 384 + 256 + c], s);
    attv[(long)blockIdx.x * C_ + c] = s;
}

// ---------------- LayerNorm over last dim (C_), optional residual add
__global__ void ln_kernel(const float* __restrict__ x, const float* __restrict__ x2,
                          const float* __restrict__ g, const float* __restrict__ b,
                          float* __restrict__ out) {
    __shared__ float red[C_];
    int r = blockIdx.x, c = threadIdx.x;
    float v = x[(long)r * C_ + c];
    if (x2) v += x2[(long)r * C_ + c];
    red[c] = v; __syncthreads();
    for (int off = 64; off; off >>= 1) { if (c < off) red[c] += red[c + off]; __syncthreads(); }
    float m = red[0] * (1.f / C_); __syncthreads();
    float d = v - m;
    red[c] = d * d; __syncthreads();
    for (int off = 64; off; off >>= 1) { if (c < off) red[c] += red[c + off]; __syncthreads(); }
    float var = red[0] * (1.f / C_);
    out[(long)r * C_ + c] = d * (1.f / sqrtf(var + 1e-5f)) * g[c] + b[c];
}

// ---------------- lat[b][c] = sum_t x2[tb][c]
__global__ void latsum_kernel(const float* __restrict__ x2, float* __restrict__ lat) {
    int b = blockIdx.x, c = threadIdx.x;
    float s = 0.f;
    for (int t = 0; t < T_; t++) s += x2[((long)t * B_ + b) * C_ + c];
    lat[(long)b * C_ + c] = s;
}

// ---------------- logit + feat_fMRI
__global__ void final_kernel(const float* __restrict__ lat, const float* __restrict__ cls_w,
                             const float* __restrict__ cls_b, float* __restrict__ out) {
    int idx = blockIdx.x * blockDim.x + threadIdx.x;
    if (idx < B_ * NC_) {
        int b = idx / NC_, nc = idx % NC_;
        float s = 0.f;
        for (int l = 0; l < L_; l++) {
            float acc = 0.f;
            for (int c = 0; c < C_; c++)
                acc = fmaf(lat[l * B_ * C_ + b * C_ + c], cls_w[l * C_ * NC_ + c * NC_ + nc], acc);
            s += acc + cls_b[l * NC_ + nc];
        }
        out[idx] = s;
    } else if (idx < B_ * NC_ + B_ * C_) {
        int j = idx - B_ * NC_;
        out[idx] = 0.5f * (lat[j] + lat[B_ * C_ + j]);
    }
}

// ---------------- feat_sMRI = bn(trad @ smri_w + smri_b) over batch of 8
__global__ void smri_kernel(const float* __restrict__ trad, const float* __restrict__ w,
                            const float* __restrict__ bias, const float* __restrict__ g,
                            const float* __restrict__ bb, float* __restrict__ out) {
    int c = threadIdx.x;
    float y[B_];
    for (int b = 0; b < B_; b++) {
        float s = bias[c];
        for (int k = 0; k < S_; k++) s = fmaf(trad[b * S_ + k], w[k * C_ + c], s);
        y[b] = s;
    }
    float m = 0.f;
    for (int b = 0; b < B_; b++) m += y[b];
    m *= (1.f / B_);
    float var = 0.f;
    for (int b = 0; b < B_; b++) { float d = y[b] - m; var += d * d; }
    var *= (1.f / B_);
    float inv = 1.f / sqrtf(var + 1e-5f);
    for (int b = 0; b < B_; b++) out[b * C_ + c] = (y[b] - m) * inv * g[c] + bb[c];
}

// ============================================================================
extern "C" void kernel_launch(void* const* d_in, const int* in_sizes, int n_in,
                              void* d_out, int out_size, void* d_ws, size_t ws_size,
                              hipStream_t stream) {
    const float* fv       = (const float*)d_in[0];
    const float* fa       = (const float*)d_in[1];
    const float* trad     = (const float*)d_in[2];
    const float* w_init   = (const float*)d_in[6];
    const float* b_init   = (const float*)d_in[7];
    const float* gin_eps  = (const float*)d_in[8];
    const float* gin_w1   = (const float*)d_in[9];
    const float* gin_b1   = (const float*)d_in[10];
    const float* gbn1g    = (const float*)d_in[11];
    const float* gbn1b    = (const float*)d_in[12];
    const float* gin_w2   = (const float*)d_in[13];
    const float* gin_b2   = (const float*)d_in[14];
    const float* gbn2g    = (const float*)d_in[15];
    const float* gbn2b    = (const float*)d_in[16];
    const float* sero_w   = (const float*)d_in[17];
    const float* sero_b   = (const float*)d_in[18];
    const float* sbng     = (const float*)d_in[19];
    const float* sbnb     = (const float*)d_in[20];
    const float* sero_aw  = (const float*)d_in[21];
    const float* sero_ab  = (const float*)d_in[22];
    const float* wqkv     = (const float*)d_in[23];
    const float* bqkv     = (const float*)d_in[24];
    const float* wo       = (const float*)d_in[25];
    const float* bo       = (const float*)d_in[26];
    const float* ln1g     = (const float*)d_in[27];
    const float* ln1b     = (const float*)d_in[28];
    const float* ln2g     = (const float*)d_in[29];
    const float* ln2b     = (const float*)d_in[30];
    const float* tw1      = (const float*)d_in[31];
    const float* tb1      = (const float*)d_in[32];
    const float* tw2      = (const float*)d_in[33];
    const float* tb2      = (const float*)d_in[34];
    const float* cls_w    = (const float*)d_in[35];
    const float* cls_b    = (const float*)d_in[36];
    const float* smri_w   = (const float*)d_in[37];
    const float* smri_b   = (const float*)d_in[38];
    const float* smri_g   = (const float*)d_in[39];
    const float* smri_bb  = (const float*)d_in[40];

    float* out = (float*)d_out;

    // workspace layout
    const long SZ_BIG = (long)RB_ * C_;            // 13,107,200 elements
    unsigned short* H3b = (unsigned short*)d_ws;   // bf16 big buffers
    unsigned short* Y1b = H3b + SZ_BIG;            // zh (row-major) / Y1raw
    unsigned short* Y2b = Y1b + SZ_BIG;            // y2
    unsigned short* ZTb = Y2b + SZ_BIG;            // zh^T: 512 x 128 x 224
    float* fbase = (float*)(ZTb + (long)BT_ * 128 * 224);
    float* THR  = fbase;                  // 512
    float* STAT = THR + 512;              // 256
    float* XR   = STAT + 256;             // 512*128
    float* E    = XR  + BT_ * C_;
    float* GA   = E   + BT_ * C_;         // 512*200
    float* HR   = GA  + BT_ * N_;
    float* QKV  = HR  + BT_ * C_;         // 512*384
    float* ATTV = QKV + BT_ * 3 * C_;
    float* ATT  = ATTV + BT_ * C_;
    float* X1   = ATT + BT_ * C_;
    float* MMB  = X1  + BT_ * C_;         // 512*256 (FFN scratch)
    float* X2   = MMB + BT_ * 2 * C_;
    float* LAT  = X2  + BT_ * C_;         // 2*8*128
    float* STATB = MMB;   // overlay: BN2 stats; lifetime disjoint from FFN scratch
    unsigned short* WT0 = (unsigned short*)(LAT + L_ * B_ * C_);  // w_init^T: 128 x 224
    unsigned short* WT1 = WT0 + 128 * 224;                        // gin_w1^T: 2 x (128x128)
    unsigned short* WT2 = WT1 + 2 * 128 * 128;                    // gin_w2^T: 2 x (128x128)
    unsigned* MSK = (unsigned*)(WT2 + 2 * 128 * 128);             // 512 x 200 x 7 words

    // output layout (floats)
    float* OUT_LOGIT = out;            // 16 logit + 1024 feat_fMRI
    float* OUT_FEATS = out + 1040;     // 1024 (feat_sMRI)
    float* OUT_NODE  = out + 2064;     // 204800
    float* OUT_TIME  = out + 206864;   // 65536

    // ---- one-shot weight transpose+cvt (tiny)
    wtcvt_kernel<<<128, 64, 0, stream>>>(w_init, 200, 224, WT0);
    wtcvt_kernel<<<128, 64, 0, stream>>>(gin_w1,           128, 128, WT1);
    wtcvt_kernel<<<128, 64, 0, stream>>>(gin_w1 + C_ * C_, 128, 128, WT1 + 128 * 128);
    wtcvt_kernel<<<128, 64, 0, stream>>>(gin_w2,           128, 128, WT2);
    wtcvt_kernel<<<128, 64, 0, stream>>>(gin_w2 + C_ * C_, 128, 128, WT2 + 128 * 128);

    // h3 = fv @ w_init + b_init   (fp32 A, K=200/Kpad224, bf16 out)
    gemm_direct_kernel<false, false, true, false><<<RB_ / 128, 256, 0, stream>>>(
        fv, 200, 200, 7, WT0, 224, b_init, nullptr, nullptr, nullptr, H3b, nullptr);
    thr_kernel<<<BT_, 512, 0, stream>>>(fa, THR, MSK);

    for (int l = 0; l < L_; l++) {
        // zh = h3 @ w1  (bf16, no bias) -> Y1b row-major
        gemm_direct_kernel<true, false, false, false><<<RB_ / 128, 256, 0, stream>>>(
            H3b, 128, 128, 4, WT1 + l * 128 * 128, 128,
            nullptr, nullptr, nullptr, nullptr, Y1b, nullptr);
        // zh -> zh^T (per bt, zero-padded to K=224)
        zt_kernel<<<BT_, 256, 0, stream>>>(Y1b, ZTb);
        // y2 = (mask + eps I) @ zh + b1, fused BN1 stats
        hipMemsetAsync(STAT, 0, 256 * sizeof(float), stream);
        maskagg_kernel<<<BT_ * 2, 256, 0, stream>>>(MSK, ZTb, gin_eps, l, gin_b1 + l * C_, Y2b, STAT);
        // Y1raw = relu(bn1(y2)) @ w2 + b2, fused BN2 stats
        hipMemsetAsync(STATB, 0, 256 * sizeof(float), stream);
        gemm_direct_kernel<true, true, true, true><<<RB_ / 128, 256, 0, stream>>>(
            Y2b, 128, 128, 4, WT2 + l * 128 * 128, 128, gin_b2 + l * C_, STAT,
            gbn1g + l * C_, gbn1b + l * C_, Y1b, STATB);
        // hb = relu(bn2(Y1raw)) applied on-the-fly in xr2/hr2
        xr2_kernel<<<BT_, 128, 0, stream>>>(Y1b, STATB, gbn2g + l * C_, gbn2b + l * C_, XR);

        mm_kernel<128, 8><<<BT_ / 8, 128, 0, stream>>>(XR, sero_w + l * C_ * C_, sero_b + l * C_, E, C_, ACT_NONE);
        hipMemsetAsync(STAT, 0, 256 * sizeof(float), stream);
        colstats_kernel<<<2, 256, 0, stream>>>(E, 256, BT_, STAT);
        bnact_kernel<<<(BT_ * C_) / 256, 256, 0, stream>>>(E, BT_, STAT, sbng + l * C_, sbnb + l * C_, ACT_GELU);

        ga_kernel<<<BT_ / 8, 256, 0, stream>>>(E, sero_aw + l * C_ * N_, sero_ab + l * N_, GA, OUT_NODE, l);
        hr2_kernel<<<BT_, 128, 0, stream>>>(Y1b, STATB, gbn2g + l * C_, gbn2b + l * C_, GA, HR);

        mm_kernel<128, 8><<<BT_ / 8, 384, 0, stream>>>(HR, wqkv + l * C_ * 3 * C_, bqkv + l * 3 * C_, QKV, 3 * C_, ACT_NONE);
        attn_kernel<<<B_ * T_, 64, 0, stream>>>(QKV, OUT_TIME, l);
        attv_kernel<<<BT_, 128, 0, stream>>>(OUT_TIME, QKV, ATTV, l);
        mm_kernel<128, 8><<<BT_ / 8, 128, 0, stream>>>(ATTV, wo + l * C_ * C_, bo + l * C_, ATT, C_, ACT_NONE);
        ln_kernel<<<BT_, 128, 0, stream>>>(ATT, nullptr, ln1g + l * C_, ln1b + l * C_, X1);
        mm_kernel<128, 8><<<BT_ / 8, 256, 0, stream>>>(X1, tw1 + l * C_ * 2 * C_, tb1 + l * 2 * C_, MMB, 2 * C_, ACT_RELU);
        mm_kernel<256, 8><<<BT_ / 8, 128, 0, stream>>>(MMB, tw2 + l * 2 * C_ * C_, tb2 + l * C_, ATTV, C_, ACT_NONE);
        ln_kernel<<<BT_, 128, 0, stream>>>(X1, ATTV, ln2g + l * C_, ln2b + l * C_, X2);
        latsum_kernel<<<B_, 128, 0, stream>>>(X2, LAT + l * B_ * C_);
    }

    final_kernel<<<5, 256, 0, stream>>>(LAT, cls_w, cls_b, OUT_LOGIT);
    smri_kernel<<<1, 128, 0, stream>>>(trad, smri_w, smri_b, smri_g, smri_bb, OUT_FEATS);
}